// Round 5
// baseline (942.635 us; speedup 1.0000x reference)
//
#include <hip/hip_runtime.h>

// Problem constants
#define BB    16
#define CC    256               // channels == embed dim
#define HWD   1024              // 32*32
#define NN    16384             // BB*HWD rows
#define KK    8192              // codebook size
#define DD    256               // embed dim
#define ZQ_N  4194304           // BB*CC*HWD output elements

// Workspace layout (bytes) -- TOTAL 131,080 B (proven)
#define WS_ROWBEST 0            // u64 rowBest[NN]   131,072 B
#define WS_LOSS    131072       // double lossSum          8 B
#define WS_NEEDED  131080

// Scratch inside d_out (float-index units). out_size = 4,210,691 floats.
#define ZB_OFF      0           // ushort zb[NN*DD]     floats [0 .. 2,097,152)
#define EB_OFF      2097152     // ushort eb[KK*DD]     floats [.. 3,145,728)
#define Q_OFF       3145728     // uint2 queue[128][SEGCAP]  (1,046,528 u32)
#define SEGCNT_OFF  4192256     // u32 segCnt[128]
#define BC_OFF      4194304     // u32 bestC[NN]        floats [.. 4,210,688)
#define SEGCAP      4088u       // entries per row-block segment (8B each)
#define LQCAP       768         // per-block LDS candidate list (exact overflow fallback)

#define CMARGIN  4e-4f   // >= 2*eps_tot (bf16 dot ~1e-4 + numpy-vs-coarse ~6.5e-5 + e2-omit 4e-6)

typedef short short8 __attribute__((ext_vector_type(8)));
typedef float f32x4  __attribute__((ext_vector_type(4)));
typedef unsigned short u16;
typedef unsigned int   u32;

// ---- helpers ----
static __device__ __forceinline__ u32 cenc(float x) {   // sortable f32
    u32 u = __float_as_uint(x);
    return (u & 0x80000000u) ? ~u : (u | 0x80000000u);
}
static __device__ __forceinline__ float cdec(u32 k) {
    u32 u = (k & 0x80000000u) ? (k ^ 0x80000000u) : ~k;
    return __uint_as_float(u);
}
static __device__ __forceinline__ u16 f2bf(float f) {    // RNE f32->bf16
    u32 u = __float_as_uint(f);
    return (u16)((u + 0x7FFFu + ((u >> 16) & 1u)) >> 16);
}

__global__ void k_init(unsigned long long* __restrict__ rowBest, double* __restrict__ lossSum,
                       u32* __restrict__ bestC, u32* __restrict__ segCnt) {
    int i = blockIdx.x * 256 + threadIdx.x;
    if (i < NN) {
        rowBest[i] = (((unsigned long long)0xFF800000u) << 24) | 0xFFFFFFULL; // +inf key
        bestC[i]   = 0xFFFFFFFFu;   // decodes NaN; all bound math NaN-safe (fminf)
    }
    if (i < 128) segCnt[i] = 0u;
    if (i == 128) *lossSum = 0.0;
}

// z [b][d][hw] f32 -> zb16T [b*1024+hw][d] bf16  (LDS-tiled transpose+convert)
__global__ void k_cvt_z(const float* __restrict__ z, u16* __restrict__ zb) {
    __shared__ float tile[64][65];
    const int b = blockIdx.z, d0 = blockIdx.y * 64, h0 = blockIdx.x * 64;
    const int t = threadIdx.x;
    const float* zp = z + ((size_t)b * CC + d0) * HWD + h0;
#pragma unroll
    for (int i = 0; i < 4; ++i) {
        int fid = i * 256 + t;
        int dd = fid >> 4, hq = (fid & 15) * 4;
        float4 v = *(const float4*)(zp + (size_t)dd * HWD + hq);
        tile[dd][hq] = v.x; tile[dd][hq + 1] = v.y; tile[dd][hq + 2] = v.z; tile[dd][hq + 3] = v.w;
    }
    __syncthreads();
    u16* op = zb + ((size_t)b * HWD + h0) * DD + d0;
#pragma unroll
    for (int i = 0; i < 4; ++i) {
        int fid = i * 256 + t;
        int hh = fid >> 4, dq = (fid & 15) * 4;
        ushort4 o;
        o.x = f2bf(tile[dq + 0][hh]); o.y = f2bf(tile[dq + 1][hh]);
        o.z = f2bf(tile[dq + 2][hh]); o.w = f2bf(tile[dq + 3][hh]);
        *(ushort4*)(op + (size_t)hh * DD + dq) = o;
    }
}

// emb f32 -> eb16 bf16 (straight stream)
__global__ void k_cvt_e(const float* __restrict__ emb, u16* __restrict__ eb) {
    int i = blockIdx.x * 256 + threadIdx.x;
    float4 v = ((const float4*)emb)[i];
    ushort4 o;
    o.x = f2bf(v.x); o.y = f2bf(v.y); o.z = f2bf(v.z); o.w = f2bf(v.w);
    ((ushort4*)eb)[i] = o;
}

#define VMW8()  asm volatile("s_waitcnt vmcnt(8)"  ::: "memory")
#define VMW4()  asm volatile("s_waitcnt vmcnt(4)"  ::: "memory")
#define VMW0()  asm volatile("s_waitcnt vmcnt(0)"  ::: "memory")
#define LKW()   asm volatile("s_waitcnt lgkmcnt(0)" ::: "memory")
#define SBAR()  __builtin_amdgcn_s_barrier()

// bf16 MFMA coarse GEMM: each block computes 128x256 output (two 128-col
// halves sequentially; acc stays 64 regs -> occupancy unchanged), fed by ONE
// continuous 16-phase / 3-buffer counted-vmcnt ring (vmcnt(8), never drained
// mid-loop).  Mid-epilogue after phase 8 (half-0 acc complete): r0-proven
// RETURNING atomicMin bound + wave-aggregated direct-to-segment scan (the 3
// ring buffers have in-flight gload_lds writes, so no LDS list here), acc
// reset.  Final epilogue: returning atomicMin covering both halves, LDS list
// + single reservation (r0 path).  4096 blocks instead of 8192 amortizes the
// per-block fixed cost.
__global__ __launch_bounds__(256, 3)
void k_gemm(const u16* __restrict__ zb, const u16* __restrict__ eb,
            u32* __restrict__ bestC, u32* __restrict__ segCnt, uint2* __restrict__ queue) {
    // 3 ring buffers x (A 8KB + B 8KB) = 48KB
    __shared__ __align__(16) char smem[49152];
    __shared__ float rm0w[128][2];   // half-0 per-(row,wx) mins (live across half 1)
    __shared__ float bnd0[128];      // half-0 scan bound
    __shared__ u32 lqn, qbase;

    // Supertile XCD swizzle: XCD x owns col-supertiles [4x,4x+4) of 32;
    // row-tiles in supertiles of 16.
    const int bid = blockIdx.x;                   // 0..4095
    const int xcd = bid & 7, idx = bid >> 3;      // idx 0..511
    const int bx = (idx >> 6) * 16 + (idx & 15);  // row-tile 0..127
    const int by = xcd * 4 + ((idx >> 4) & 3);    // col-supertile 0..31
    const int row0 = bx * 128, col0 = by * 256;

    const int t = threadIdx.x;
    const int wid = t >> 6, l = t & 63;
    const int wy = wid >> 1, wx = wid & 1;    // wave grid 2x2, each wave 64x64 out

    f32x4 acc[4][4];
#pragma unroll
    for (int mi = 0; mi < 4; ++mi)
#pragma unroll
        for (int ni = 0; ni < 4; ++ni) acc[mi][ni] = (f32x4){0.f, 0.f, 0.f, 0.f};

    const int rbase = wid * 32;                       // this wave's staging rows
    // Stage: 64B rows; LDS[r][c] holds global chunk c ^ ((r>>1)&3).
    const int srow   = l >> 2;
    const int schunk = (l & 3) ^ ((l >> 3) & 3);      // lane-constant
    // Read: chunk g=(l>>4) of row base+(l&15) lives at ((l>>4)^((l>>1)&3))<<4
    const int rchunk = (((l >> 4) ^ ((l >> 1) & 3)) << 4);
    const int rrow   = l & 15;

    auto stage = [&](int buf, int half, int kc) {
        char* As = smem + buf * 16384;
        char* Bs = As + 8192;
        const int cb = col0 + half * 128;
#pragma unroll
        for (int j = 0; j < 2; ++j) {                 // 16 rows per instr
            const int rl = rbase + j * 16 + srow;
            const u16* gA = zb + (size_t)(row0 + rl) * DD + kc + schunk * 8;
            const u16* gB = eb + (size_t)(cb + rl) * DD + kc + schunk * 8;
            __builtin_amdgcn_global_load_lds(
                (const __attribute__((address_space(1))) u32*)gA,
                (__attribute__((address_space(3))) u32*)(As + (rbase + j * 16) * 64), 16, 0, 0);
            __builtin_amdgcn_global_load_lds(
                (const __attribute__((address_space(1))) u32*)gB,
                (__attribute__((address_space(3))) u32*)(Bs + (rbase + j * 16) * 64), 16, 0, 0);
        }
    };

    auto compute = [&](int buf) {
        const char* As = smem + buf * 16384;
        const char* Bs = As + 8192;
        short8 a[4], b[4];
#pragma unroll
        for (int mi = 0; mi < 4; ++mi)
            a[mi] = *(const short8*)(As + (wy * 64 + mi * 16 + rrow) * 64 + rchunk);
#pragma unroll
        for (int ni = 0; ni < 4; ++ni)
            b[ni] = *(const short8*)(Bs + (wx * 64 + ni * 16 + rrow) * 64 + rchunk);
        __builtin_amdgcn_s_setprio(1);
#pragma unroll
        for (int mi = 0; mi < 4; ++mi)
#pragma unroll
            for (int ni = 0; ni < 4; ++ni)
                acc[mi][ni] = __builtin_amdgcn_mfma_f32_16x16x32_bf16(a[mi], b[ni], acc[mi][ni], 0, 0, 0);
        __builtin_amdgcn_s_setprio(0);
    };

    uint2* qseg = queue + (size_t)bx * SEGCAP;

    // ---- continuous 16-phase ring: tiles 0..7 = half 0, 8..15 = half 1 ----
    stage(0, 0, 0); stage(1, 0, 32); stage(2, 0, 64);
    VMW8(); SBAR(); compute(0); LKW(); SBAR(); stage(0, 0, 96);
    VMW8(); SBAR(); compute(1); LKW(); SBAR(); stage(1, 0, 128);
    VMW8(); SBAR(); compute(2); LKW(); SBAR(); stage(2, 0, 160);
    VMW8(); SBAR(); compute(0); LKW(); SBAR(); stage(0, 0, 192);
    VMW8(); SBAR(); compute(1); LKW(); SBAR(); stage(1, 0, 224);
    VMW8(); SBAR(); compute(2); LKW(); SBAR(); stage(2, 1, 0);
    VMW8(); SBAR(); compute(0); LKW(); SBAR(); stage(0, 1, 32);
    VMW8(); SBAR(); compute(1); LKW(); SBAR(); stage(1, 1, 64);

    // ---- mid-epilogue: half-0 acc complete; tiles 8..10 still in flight ----
    {
        // per-row half-0 min (= -2 * max dot) over this wave's 64 cols
#pragma unroll
        for (int mi = 0; mi < 4; ++mi)
#pragma unroll
            for (int r = 0; r < 4; ++r) {
                float v = fmaxf(fmaxf(acc[mi][0][r], acc[mi][1][r]), fmaxf(acc[mi][2][r], acc[mi][3][r]));
                v = fmaxf(v, __shfl_xor(v, 1));
                v = fmaxf(v, __shfl_xor(v, 2));
                v = fmaxf(v, __shfl_xor(v, 4));
                v = fmaxf(v, __shfl_xor(v, 8));
                if ((l & 15) == 0)
                    rm0w[wy * 64 + mi * 16 + ((l >> 4) << 2) + r][wx] = -2.0f * v;
            }
        LKW(); SBAR();
        // r0-proven fresh bound: ONE returning atomicMin per row per block
        if (t < 128) {
            float mn = fminf(rm0w[t][0], rm0w[t][1]);
            u32 old = atomicMin(bestC + row0 + t, cenc(mn));
            bnd0[t] = fminf(mn, cdec(old));             // NaN-safe: fminf(x,NaN)=x
        }
        LKW(); SBAR();
        // scan half-0 candidates -> global segment, wave-aggregated atomics
#pragma unroll
        for (int mi = 0; mi < 4; ++mi)
#pragma unroll
            for (int r = 0; r < 4; ++r) {
                const int rl = wy * 64 + mi * 16 + ((l >> 4) << 2) + r;
                const float cut = bnd0[rl] + CMARGIN;
                const int row = row0 + rl;
#pragma unroll
                for (int ni = 0; ni < 4; ++ni) {
                    const float s = -2.0f * acc[mi][ni][r];
                    const bool p = (s <= cut);
                    unsigned long long msk = __ballot(p);
                    if (msk) {
                        const u32 cnt = (u32)__popcll(msk);
                        const int ldr = __ffsll((unsigned long long)msk) - 1;
                        u32 base = 0;
                        if (l == ldr) base = atomicAdd(segCnt + bx, cnt);
                        base = __shfl(base, ldr);
                        if (p) {
                            const u32 gi = base + (u32)__popcll(msk & ((1ULL << l) - 1ULL));
                            const int col = col0 + wx * 64 + ni * 16 + (l & 15);
                            if (gi < SEGCAP)
                                qseg[gi] = make_uint2(((u32)row << 13) | (u32)col, __float_as_uint(s));
                        }
                    }
                }
            }
        // reset accumulators for half 1
#pragma unroll
        for (int mi = 0; mi < 4; ++mi)
#pragma unroll
            for (int ni = 0; ni < 4; ++ni) acc[mi][ni] = (f32x4){0.f, 0.f, 0.f, 0.f};
    }

    VMW8(); SBAR(); compute(2); LKW(); SBAR(); stage(2, 1, 96);
    VMW8(); SBAR(); compute(0); LKW(); SBAR(); stage(0, 1, 128);
    VMW8(); SBAR(); compute(1); LKW(); SBAR(); stage(1, 1, 160);
    VMW8(); SBAR(); compute(2); LKW(); SBAR(); stage(2, 1, 192);
    VMW8(); SBAR(); compute(0); LKW(); SBAR(); stage(0, 1, 224);
    VMW8(); SBAR(); compute(1);
    VMW4(); SBAR(); compute(2);
    VMW0(); SBAR(); compute(0);

    // ---- final epilogue: scratch aliases ring buf1 (dead; last compute read
    // buf0, compute(1) was 2 barriers ago).  rm @ +16384, lqe/lqs follow.
    float* rm = (float*)(smem + 16384);
    u32* lqe  = (u32*)(smem + 17408);
    u32* lqs  = lqe + LQCAP;

#pragma unroll
    for (int mi = 0; mi < 4; ++mi)
#pragma unroll
        for (int r = 0; r < 4; ++r) {
            float v = fmaxf(fmaxf(acc[mi][0][r], acc[mi][1][r]), fmaxf(acc[mi][2][r], acc[mi][3][r]));
            v = fmaxf(v, __shfl_xor(v, 1));
            v = fmaxf(v, __shfl_xor(v, 2));
            v = fmaxf(v, __shfl_xor(v, 4));
            v = fmaxf(v, __shfl_xor(v, 8));
            if ((l & 15) == 0)
                rm[(wy * 64 + mi * 16 + ((l >> 4) << 2) + r) * 2 + wx] = -2.0f * v;
        }
    if (t == 0) lqn = 0;
    __syncthreads();

    // fresh bound covering BOTH halves: ONE returning atomicMin per row
    if (t < 128) {
        float mn1 = fminf(rm[t * 2], rm[t * 2 + 1]);
        float mnA = fminf(mn1, fminf(rm0w[t][0], rm0w[t][1]));
        u32 old = atomicMin(bestC + row0 + t, cenc(mnA));
        rm[t * 2] = fminf(mnA, cdec(old));   // NaN-safe
    }
    __syncthreads();

    // half-1 candidates -> LDS list; exact overflow -> direct global slot
#pragma unroll
    for (int mi = 0; mi < 4; ++mi)
#pragma unroll
        for (int r = 0; r < 4; ++r) {
            const int rl = wy * 64 + mi * 16 + ((l >> 4) << 2) + r;
            const float cut = rm[rl * 2] + CMARGIN;
            const int row = row0 + rl;
#pragma unroll
            for (int ni = 0; ni < 4; ++ni) {
                const float s = -2.0f * acc[mi][ni][r];
                if (s <= cut) {
                    const int col = col0 + 128 + wx * 64 + ni * 16 + (l & 15);
                    u32 li = atomicAdd(&lqn, 1u);
                    if (li < LQCAP) {
                        lqe[li] = ((u32)row << 13) | (u32)col;
                        lqs[li] = __float_as_uint(s);
                    } else {
                        u32 gi = atomicAdd(segCnt + bx, 1u);   // rare exact fallback
                        if (gi < SEGCAP)
                            qseg[gi] = make_uint2(((u32)row << 13) | (u32)col, __float_as_uint(s));
                    }
                }
            }
        }
    __syncthreads();
    if (t == 0) {
        u32 n = min(lqn, (u32)LQCAP);
        lqn = n;
        qbase = atomicAdd(segCnt + bx, n);  // single reservation into row-block segment
    }
    __syncthreads();
    for (u32 i2 = t; i2 < lqn; i2 += 256) {
        u32 gi = qbase + i2;
        if (gi < SEGCAP) qseg[gi] = make_uint2(lqe[i2], lqs[i2]);
    }
}

// Four blocks per row-block segment (interleaved entries): survivors share a
// 128-row z window -> L2-reused strided reads.
// Filter by stored coarse score vs final bestC; numpy-fp32 replica on survivors.
__global__ __launch_bounds__(512)
void k_rescore(const float* __restrict__ z, const float* __restrict__ emb,
               const uint2* __restrict__ queue, const u32* __restrict__ segCnt,
               const u32* __restrict__ bestC,
               unsigned long long* __restrict__ rowBest) {
    const int seg = blockIdx.x >> 2;
    const int part = blockIdx.x & 3;
    const u32 n = min(segCnt[seg], SEGCAP);
    const uint2* q = queue + (size_t)seg * SEGCAP;
    for (u32 i = part * 512 + threadIdx.x; i < n; i += 2048) {
        const uint2 ent = q[i];
        const int row = (int)(ent.x >> 13), col = (int)(ent.x & 8191u);
        const float s = __uint_as_float(ent.y);
        const float bound = cdec(bestC[row]);      // final global coarse min (finite)
        if (s > bound + CMARGIN) continue;

        // ---- bit-exact numpy fp32 replica (validated rounds 5-8) ----
        const int b = row >> 10, hw = row & 1023;
        const float* zr = z + (size_t)b * CC * HWD + hw;   // element d at zr[d*HWD]
        const float* er = emb + (size_t)col * DD;

        float A0 = 0.f, A1 = 0.f, A2 = 0.f, A3 = 0.f;
        float zh0 = 0.f, eh0 = 0.f, z2 = 0.f, e2 = 0.f;
#pragma unroll
        for (int h = 0; h < 2; ++h) {
            const int base = h * 128;
            float zv[8], ev[8], rz[8], re[8];
#pragma unroll
            for (int q2 = 0; q2 < 8; ++q2) { zv[q2] = zr[(size_t)(base + q2) * HWD]; ev[q2] = er[base + q2]; }
#pragma unroll
            for (int q2 = 0; q2 < 8; ++q2) { rz[q2] = __fmul_rn(zv[q2], zv[q2]); re[q2] = __fmul_rn(ev[q2], ev[q2]); }
            A0 = __fadd_rn(A0, __fmul_rn(zv[0], ev[0])); A1 = __fadd_rn(A1, __fmul_rn(zv[1], ev[1]));
            A2 = __fadd_rn(A2, __fmul_rn(zv[2], ev[2])); A3 = __fadd_rn(A3, __fmul_rn(zv[3], ev[3]));
            A0 = __fadd_rn(A0, __fmul_rn(zv[4], ev[4])); A1 = __fadd_rn(A1, __fmul_rn(zv[5], ev[5]));
            A2 = __fadd_rn(A2, __fmul_rn(zv[6], ev[6])); A3 = __fadd_rn(A3, __fmul_rn(zv[7], ev[7]));
            for (int i2 = 8; i2 < 128; i2 += 8) {
#pragma unroll
                for (int q2 = 0; q2 < 8; ++q2) { zv[q2] = zr[(size_t)(base + i2 + q2) * HWD]; ev[q2] = er[base + i2 + q2]; }
#pragma unroll
                for (int q2 = 0; q2 < 8; ++q2) {
                    rz[q2] = __fadd_rn(rz[q2], __fmul_rn(zv[q2], zv[q2]));
                    re[q2] = __fadd_rn(re[q2], __fmul_rn(ev[q2], ev[q2]));
                }
                A0 = __fadd_rn(A0, __fmul_rn(zv[0], ev[0])); A1 = __fadd_rn(A1, __fmul_rn(zv[1], ev[1]));
                A2 = __fadd_rn(A2, __fmul_rn(zv[2], ev[2])); A3 = __fadd_rn(A3, __fmul_rn(zv[3], ev[3]));
                A0 = __fadd_rn(A0, __fmul_rn(zv[4], ev[4])); A1 = __fadd_rn(A1, __fmul_rn(zv[5], ev[5]));
                A2 = __fadd_rn(A2, __fmul_rn(zv[6], ev[6])); A3 = __fadd_rn(A3, __fmul_rn(zv[7], ev[7]));
            }
            float cz = __fadd_rn(__fadd_rn(__fadd_rn(rz[0], rz[1]), __fadd_rn(rz[2], rz[3])),
                                 __fadd_rn(__fadd_rn(rz[4], rz[5]), __fadd_rn(rz[6], rz[7])));
            float ce = __fadd_rn(__fadd_rn(__fadd_rn(re[0], re[1]), __fadd_rn(re[2], re[3])),
                                 __fadd_rn(__fadd_rn(re[4], re[5]), __fadd_rn(re[6], re[7])));
            if (h == 0) { zh0 = cz; eh0 = ce; }
            else        { z2 = __fadd_rn(zh0, cz); e2 = __fadd_rn(eh0, ce); }
        }
        const float dot = __fadd_rn(__fadd_rn(A0, A1), __fadd_rn(A2, A3));
        const float S   = __fadd_rn(z2, e2);
        const float d   = __fsub_rn(S, __fmul_rn(2.0f, dot));

        const u32 db = __float_as_uint(d);
        const u32 kd = (db & 0x80000000u) ? ~db : (db | 0x80000000u);
        const unsigned long long pk = (((unsigned long long)kd) << 24) | (unsigned long long)col;
        atomicMin(rowBest + row, pk);   // fp32-equal d -> smaller col = numpy first-index
    }
}

__global__ void k_ids(const unsigned long long* __restrict__ rowBest,
                      float* __restrict__ outIds) {
    int n = blockIdx.x * 256 + threadIdx.x;
    if (n < NN) outIds[n] = (float)((int)(rowBest[n] & 0xFFFFFFULL) & (KK - 1));
}

// Coalesced z_q gather: block = (64-hw tile, b, c-half). Stage the 64 needed
// emb rows (one 128-col half) in LDS [64][129] (pad -> conflict-free column
// reads), coalesced global reads; write out[b][c][hw0..hw0+63] as 256B runs.
// Fused fp64 loss.
__global__ __launch_bounds__(256)
void k_gather(const float* __restrict__ z, const float* __restrict__ emb,
              const unsigned long long* __restrict__ rowBest,
              float* __restrict__ outZq, double* __restrict__ lossSum) {
    __shared__ float lt[64][129];
    __shared__ u32 idr[64];
    __shared__ double red[4];
    const int t = threadIdx.x;
    const int hw0 = blockIdx.x * 64, b = blockIdx.y;
    const int h2 = blockIdx.z;                // channel half 0/1
    const int w = t >> 6, l = t & 63;

    if (t < 64)
        idr[t] = (u32)(rowBest[b * HWD + hw0 + t] & 0xFFFFFFULL) & (KK - 1);
    __syncthreads();

    const int rr = t >> 7, cc = t & 127;
    for (int s = 0; s < 32; ++s) {
        const int r = s * 2 + rr;
        lt[r][cc] = emb[(size_t)idr[r] * DD + h2 * 128 + cc];
    }
    __syncthreads();

    double lsum = 0.0;
#pragma unroll
    for (int i = 0; i < 32; ++i) {
        const int cl = i * 4 + w;
        const int c  = h2 * 128 + cl;
        const size_t f = ((size_t)(b * CC + c)) * HWD + hw0 + l;
        const float zq = lt[l][cl];
        const float zv = z[f];
        outZq[f] = zq;
        const double dif = (double)zq - (double)zv;
        lsum += dif * dif;
    }
#pragma unroll
    for (int o = 32; o; o >>= 1) lsum += __shfl_down(lsum, o);
    if (l == 0) red[w] = lsum;
    __syncthreads();
    if (t == 0) atomicAdd(lossSum, red[0] + red[1] + red[2] + red[3]);
}

__global__ void k_loss(const double* __restrict__ lossSum, float* __restrict__ outLoss) {
    double m = *lossSum / (double)ZQ_N;
    outLoss[0] = (float)(1.25 * m);   // loss = commitment + codebook
    outLoss[1] = (float)(0.25 * m);   // commitment (cost 0.25)
    outLoss[2] = (float)m;            // codebook
}

extern "C" void kernel_launch(void* const* d_in, const int* in_sizes, int n_in,
                              void* d_out, int out_size, void* d_ws, size_t ws_size,
                              hipStream_t stream) {
    const float* z   = (const float*)d_in[0];
    const float* emb = (const float*)d_in[1];
    float* out = (float*)d_out;
    char* ws = (char*)d_ws;

    if (ws_size < (size_t)WS_NEEDED) return;

    unsigned long long* rowBest = (unsigned long long*)(ws + WS_ROWBEST);
    double*             lossSum = (double*)(ws + WS_LOSS);
    u16*   zb     = (u16*)(out + ZB_OFF);
    u16*   eb     = (u16*)(out + EB_OFF);
    uint2* queue  = (uint2*)(out + Q_OFF);
    u32*   segCnt = (u32*)(out + SEGCNT_OFF);
    u32*   bestC  = (u32*)(out + BC_OFF);

    hipLaunchKernelGGL(k_init,    dim3(64),          dim3(256), 0, stream, rowBest, lossSum, bestC, segCnt);
    hipLaunchKernelGGL(k_cvt_z,   dim3(16, 4, 16),   dim3(256), 0, stream, z, zb);
    hipLaunchKernelGGL(k_cvt_e,   dim3(2048),        dim3(256), 0, stream, emb, eb);
    hipLaunchKernelGGL(k_gemm,    dim3(4096),        dim3(256), 0, stream, zb, eb, bestC, segCnt, queue);
    hipLaunchKernelGGL(k_rescore, dim3(512),         dim3(512), 0, stream, z, emb, queue, segCnt, bestC, rowBest);
    hipLaunchKernelGGL(k_ids,     dim3(64),          dim3(256), 0, stream, rowBest, out + ZQ_N + 3);
    hipLaunchKernelGGL(k_gather,  dim3(16, 16, 2),   dim3(256), 0, stream, z, emb, rowBest, out, lossSum);
    hipLaunchKernelGGL(k_loss,    dim3(1),           dim3(1),   0, stream, lossSum, out + ZQ_N);
}

// Round 6
// 348.083 us; speedup vs baseline: 2.7081x; 2.7081x over previous
//
#include <hip/hip_runtime.h>

// Problem constants
#define BB    16
#define CC    256               // channels == embed dim
#define HWD   1024              // 32*32
#define NN    16384             // BB*HWD rows
#define KK    8192              // codebook size
#define DD    256               // embed dim
#define ZQ_N  4194304           // BB*CC*HWD output elements

// Workspace layout (bytes) -- TOTAL 131,080 B (proven)
#define WS_ROWBEST 0            // u64 rowBest[NN]   131,072 B
#define WS_LOSS    131072       // double lossSum          8 B
#define WS_NEEDED  131080

// Scratch inside d_out (float-index units). out_size = 4,210,691 floats.
#define ZB_OFF      0           // ushort zb[NN*DD]     floats [0 .. 2,097,152)
#define EB_OFF      2097152     // ushort eb[KK*DD]     floats [.. 3,145,728)
#define Q_OFF       3145728     // uint2 queue[128][SEGCAP]  (1,046,528 u32)
#define SEGCNT_OFF  4192256     // u32 segCnt[128]
#define BC_OFF      4194304     // u32 bestC[NN]        floats [.. 4,210,688)
#define SEGCAP      4088u       // entries per row-block segment (8B each)
#define LQCAP       768         // per-block LDS candidate list (exact overflow fallback)

#define CMARGIN  4e-4f   // >= 2*eps_tot (bf16 dot ~1e-4 + numpy-vs-coarse ~6.5e-5 + e2-omit 4e-6)

typedef short short8 __attribute__((ext_vector_type(8)));
typedef float f32x4  __attribute__((ext_vector_type(4)));
typedef unsigned short u16;
typedef unsigned int   u32;

// ---- helpers ----
static __device__ __forceinline__ u32 cenc(float x) {   // sortable f32
    u32 u = __float_as_uint(x);
    return (u & 0x80000000u) ? ~u : (u | 0x80000000u);
}
static __device__ __forceinline__ float cdec(u32 k) {
    u32 u = (k & 0x80000000u) ? (k ^ 0x80000000u) : ~k;
    return __uint_as_float(u);
}
static __device__ __forceinline__ u16 f2bf(float f) {    // RNE f32->bf16
    u32 u = __float_as_uint(f);
    return (u16)((u + 0x7FFFu + ((u >> 16) & 1u)) >> 16);
}

__global__ void k_init(unsigned long long* __restrict__ rowBest, double* __restrict__ lossSum,
                       u32* __restrict__ bestC, u32* __restrict__ segCnt) {
    int i = blockIdx.x * 256 + threadIdx.x;
    if (i < NN) {
        rowBest[i] = (((unsigned long long)0xFF800000u) << 24) | 0xFFFFFFULL; // +inf key
        bestC[i]   = 0xFFFFFFFFu;   // decodes NaN; all bound math NaN-safe (fminf)
    }
    if (i < 128) segCnt[i] = 0u;
    if (i == 128) *lossSum = 0.0;
}

// z [b][d][hw] f32 -> zb16T [b*1024+hw][d] bf16  (LDS-tiled transpose+convert)
__global__ void k_cvt_z(const float* __restrict__ z, u16* __restrict__ zb) {
    __shared__ float tile[64][65];
    const int b = blockIdx.z, d0 = blockIdx.y * 64, h0 = blockIdx.x * 64;
    const int t = threadIdx.x;
    const float* zp = z + ((size_t)b * CC + d0) * HWD + h0;
#pragma unroll
    for (int i = 0; i < 4; ++i) {
        int fid = i * 256 + t;
        int dd = fid >> 4, hq = (fid & 15) * 4;
        float4 v = *(const float4*)(zp + (size_t)dd * HWD + hq);
        tile[dd][hq] = v.x; tile[dd][hq + 1] = v.y; tile[dd][hq + 2] = v.z; tile[dd][hq + 3] = v.w;
    }
    __syncthreads();
    u16* op = zb + ((size_t)b * HWD + h0) * DD + d0;
#pragma unroll
    for (int i = 0; i < 4; ++i) {
        int fid = i * 256 + t;
        int hh = fid >> 4, dq = (fid & 15) * 4;
        ushort4 o;
        o.x = f2bf(tile[dq + 0][hh]); o.y = f2bf(tile[dq + 1][hh]);
        o.z = f2bf(tile[dq + 2][hh]); o.w = f2bf(tile[dq + 3][hh]);
        *(ushort4*)(op + (size_t)hh * DD + dq) = o;
    }
}

// emb f32 -> eb16 bf16 (straight stream)
__global__ void k_cvt_e(const float* __restrict__ emb, u16* __restrict__ eb) {
    int i = blockIdx.x * 256 + threadIdx.x;
    float4 v = ((const float4*)emb)[i];
    ushort4 o;
    o.x = f2bf(v.x); o.y = f2bf(v.y); o.z = f2bf(v.z); o.w = f2bf(v.w);
    ((ushort4*)eb)[i] = o;
}

// bf16 MFMA coarse GEMM, 128x128 tile, 4 waves -- ZERO-LDS ZERO-BARRIER K-loop.
// Each MFMA fragment is a perfectly coalesced direct global load (lane l reads
// 16B at row*512 + (l>>4)*16; lanes {c,c+16,c+32,c+48} cover one 64B line), so
// operands stream L2->VGPR with no staging, no gload_lds, no ds_read, no
// s_barrier.  Explicit 2-deep register ping-pong (issue loads for k+2 between
// mf(k) and mf(k+1)); waves fully self-paced, latency hidden by TLP (12
// waves/CU).  Fragment contents + accumulation order bitwise-identical to the
// proven r0/r3 kernels.  Epilogue = r0's proven path (returning atomicMin per
// row, LDS candidate list, single reservation, exact overflow fallback).
__global__ __launch_bounds__(256, 3)
void k_gemm(const u16* __restrict__ zb, const u16* __restrict__ eb,
            u32* __restrict__ bestC, u32* __restrict__ segCnt, uint2* __restrict__ queue) {
    __shared__ float rm[128][2];        // per-half row-min, then fresh bound
    __shared__ u32 lqe[LQCAP];          // block-local candidate entries
    __shared__ u32 lqs[LQCAP];          // block-local candidate coarse scores
    __shared__ u32 lqn, qbase;

    // Supertile XCD swizzle: XCD x owns col-tiles [8x,8x+8); row-tiles in
    // supertiles of 16 -> L2 working set ~1MB A + 0.5MB B.
    const int bid = blockIdx.x;
    const int xcd = bid & 7, idx = bid >> 3;
    const int bx = (idx >> 7) * 16 + (idx & 15);
    const int by = xcd * 8 + ((idx >> 4) & 7);
    const int row0 = bx * 128, col0 = by * 128;

    const int t = threadIdx.x;
    const int wid = t >> 6, l = t & 63;
    const int wy = wid >> 1, wx = wid & 1;    // wave grid 2x2, each wave 64x64 out

    f32x4 acc[4][4];
#pragma unroll
    for (int mi = 0; mi < 4; ++mi)
#pragma unroll
        for (int ni = 0; ni < 4; ++ni) acc[mi][ni] = (f32x4){0.f, 0.f, 0.f, 0.f};

    // per-lane fragment base pointers (16B-aligned)
    const u16* gA = zb + (size_t)(row0 + wy * 64 + (l & 15)) * DD + (l >> 4) * 8;
    const u16* gB = eb + (size_t)(col0 + wx * 64 + (l & 15)) * DD + (l >> 4) * 8;

    auto lda = [&](short8* d, int kc) {
#pragma unroll
        for (int mi = 0; mi < 4; ++mi)
            d[mi] = *(const short8*)(gA + (size_t)mi * 16 * DD + kc);
    };
    auto ldb = [&](short8* d, int kc) {
#pragma unroll
        for (int ni = 0; ni < 4; ++ni)
            d[ni] = *(const short8*)(gB + (size_t)ni * 16 * DD + kc);
    };
    auto mf = [&](short8* a, short8* b) {
        __builtin_amdgcn_s_setprio(1);
#pragma unroll
        for (int mi = 0; mi < 4; ++mi)
#pragma unroll
            for (int ni = 0; ni < 4; ++ni)
                acc[mi][ni] = __builtin_amdgcn_mfma_f32_16x16x32_bf16(a[mi], b[ni], acc[mi][ni], 0, 0, 0);
        __builtin_amdgcn_s_setprio(0);
    };

    short8 a0[4], b0[4], a1[4], b1[4];
    // 2-deep prefetch, then ping-pong: issue loads for k+2 after mf(k)
    lda(a0, 0);   ldb(b0, 0);
    lda(a1, 32);  ldb(b1, 32);
    mf(a0, b0);   lda(a0, 64);  ldb(b0, 64);
    mf(a1, b1);   lda(a1, 96);  ldb(b1, 96);
    mf(a0, b0);   lda(a0, 128); ldb(b0, 128);
    mf(a1, b1);   lda(a1, 160); ldb(b1, 160);
    mf(a0, b0);   lda(a0, 192); ldb(b0, 192);
    mf(a1, b1);   lda(a1, 224); ldb(b1, 224);
    mf(a0, b0);
    mf(a1, b1);

    // ---- epilogue (r0-proven path) ----
    // per-row coarse min (= -2 * max dot) over this wave's 64 cols
#pragma unroll
    for (int mi = 0; mi < 4; ++mi)
#pragma unroll
        for (int r = 0; r < 4; ++r) {
            float v = fmaxf(fmaxf(acc[mi][0][r], acc[mi][1][r]), fmaxf(acc[mi][2][r], acc[mi][3][r]));
            v = fmaxf(v, __shfl_xor(v, 1));
            v = fmaxf(v, __shfl_xor(v, 2));
            v = fmaxf(v, __shfl_xor(v, 4));
            v = fmaxf(v, __shfl_xor(v, 8));
            if ((l & 15) == 0)
                rm[wy * 64 + mi * 16 + ((l >> 4) << 2) + r][wx] = -2.0f * v;
        }
    __syncthreads();

    // fresh per-row bound: ONE coalesced returning atomicMin per row per block
    if (t < 128) {
        float mn = fminf(rm[t][0], rm[t][1]);
        u32 old = atomicMin(bestC + row0 + t, cenc(mn));
        rm[t][0] = fminf(mn, cdec(old));   // NaN-safe: fminf(x, NaN) = x
    }
    if (t == 0) lqn = 0;
    __syncthreads();

    uint2* qseg = queue + (size_t)bx * SEGCAP;

    // candidates (+scores) -> LDS list; exact overflow -> direct global slot
#pragma unroll
    for (int mi = 0; mi < 4; ++mi)
#pragma unroll
        for (int r = 0; r < 4; ++r) {
            const int rl = wy * 64 + mi * 16 + ((l >> 4) << 2) + r;
            const float cut = rm[rl][0] + CMARGIN;
            const int row = row0 + rl;
#pragma unroll
            for (int ni = 0; ni < 4; ++ni) {
                const float s = -2.0f * acc[mi][ni][r];
                if (s <= cut) {
                    const int col = col0 + wx * 64 + ni * 16 + (l & 15);
                    u32 li = atomicAdd(&lqn, 1u);
                    if (li < LQCAP) {
                        lqe[li] = ((u32)row << 13) | (u32)col;
                        lqs[li] = __float_as_uint(s);
                    } else {
                        u32 gi = atomicAdd(segCnt + bx, 1u);   // rare exact fallback
                        if (gi < SEGCAP)
                            qseg[gi] = make_uint2(((u32)row << 13) | (u32)col, __float_as_uint(s));
                    }
                }
            }
        }
    __syncthreads();
    if (t == 0) {
        u32 n = min(lqn, (u32)LQCAP);
        lqn = n;
        qbase = atomicAdd(segCnt + bx, n);  // single reservation into row-block segment
    }
    __syncthreads();
    for (u32 i2 = t; i2 < lqn; i2 += 256) {
        u32 gi = qbase + i2;
        if (gi < SEGCAP) qseg[gi] = make_uint2(lqe[i2], lqs[i2]);
    }
}

// Four blocks per row-block segment (interleaved entries): survivors share a
// 128-row z window -> L2-reused strided reads.
// Filter by stored coarse score vs final bestC; numpy-fp32 replica on survivors.
__global__ __launch_bounds__(512)
void k_rescore(const float* __restrict__ z, const float* __restrict__ emb,
               const uint2* __restrict__ queue, const u32* __restrict__ segCnt,
               const u32* __restrict__ bestC,
               unsigned long long* __restrict__ rowBest) {
    const int seg = blockIdx.x >> 2;
    const int part = blockIdx.x & 3;
    const u32 n = min(segCnt[seg], SEGCAP);
    const uint2* q = queue + (size_t)seg * SEGCAP;
    for (u32 i = part * 512 + threadIdx.x; i < n; i += 2048) {
        const uint2 ent = q[i];
        const int row = (int)(ent.x >> 13), col = (int)(ent.x & 8191u);
        const float s = __uint_as_float(ent.y);
        const float bound = cdec(bestC[row]);      // final global coarse min (finite)
        if (s > bound + CMARGIN) continue;

        // ---- bit-exact numpy fp32 replica (validated rounds 5-8) ----
        const int b = row >> 10, hw = row & 1023;
        const float* zr = z + (size_t)b * CC * HWD + hw;   // element d at zr[d*HWD]
        const float* er = emb + (size_t)col * DD;

        float A0 = 0.f, A1 = 0.f, A2 = 0.f, A3 = 0.f;
        float zh0 = 0.f, eh0 = 0.f, z2 = 0.f, e2 = 0.f;
#pragma unroll
        for (int h = 0; h < 2; ++h) {
            const int base = h * 128;
            float zv[8], ev[8], rz[8], re[8];
#pragma unroll
            for (int q2 = 0; q2 < 8; ++q2) { zv[q2] = zr[(size_t)(base + q2) * HWD]; ev[q2] = er[base + q2]; }
#pragma unroll
            for (int q2 = 0; q2 < 8; ++q2) { rz[q2] = __fmul_rn(zv[q2], zv[q2]); re[q2] = __fmul_rn(ev[q2], ev[q2]); }
            A0 = __fadd_rn(A0, __fmul_rn(zv[0], ev[0])); A1 = __fadd_rn(A1, __fmul_rn(zv[1], ev[1]));
            A2 = __fadd_rn(A2, __fmul_rn(zv[2], ev[2])); A3 = __fadd_rn(A3, __fmul_rn(zv[3], ev[3]));
            A0 = __fadd_rn(A0, __fmul_rn(zv[4], ev[4])); A1 = __fadd_rn(A1, __fmul_rn(zv[5], ev[5]));
            A2 = __fadd_rn(A2, __fmul_rn(zv[6], ev[6])); A3 = __fadd_rn(A3, __fmul_rn(zv[7], ev[7]));
            for (int i2 = 8; i2 < 128; i2 += 8) {
#pragma unroll
                for (int q2 = 0; q2 < 8; ++q2) { zv[q2] = zr[(size_t)(base + i2 + q2) * HWD]; ev[q2] = er[base + i2 + q2]; }
#pragma unroll
                for (int q2 = 0; q2 < 8; ++q2) {
                    rz[q2] = __fadd_rn(rz[q2], __fmul_rn(zv[q2], zv[q2]));
                    re[q2] = __fadd_rn(re[q2], __fmul_rn(ev[q2], ev[q2]));
                }
                A0 = __fadd_rn(A0, __fmul_rn(zv[0], ev[0])); A1 = __fadd_rn(A1, __fmul_rn(zv[1], ev[1]));
                A2 = __fadd_rn(A2, __fmul_rn(zv[2], ev[2])); A3 = __fadd_rn(A3, __fmul_rn(zv[3], ev[3]));
                A0 = __fadd_rn(A0, __fmul_rn(zv[4], ev[4])); A1 = __fadd_rn(A1, __fmul_rn(zv[5], ev[5]));
                A2 = __fadd_rn(A2, __fmul_rn(zv[6], ev[6])); A3 = __fadd_rn(A3, __fmul_rn(zv[7], ev[7]));
            }
            float cz = __fadd_rn(__fadd_rn(__fadd_rn(rz[0], rz[1]), __fadd_rn(rz[2], rz[3])),
                                 __fadd_rn(__fadd_rn(rz[4], rz[5]), __fadd_rn(rz[6], rz[7])));
            float ce = __fadd_rn(__fadd_rn(__fadd_rn(re[0], re[1]), __fadd_rn(re[2], re[3])),
                                 __fadd_rn(__fadd_rn(re[4], re[5]), __fadd_rn(re[6], re[7])));
            if (h == 0) { zh0 = cz; eh0 = ce; }
            else        { z2 = __fadd_rn(zh0, cz); e2 = __fadd_rn(eh0, ce); }
        }
        const float dot = __fadd_rn(__fadd_rn(A0, A1), __fadd_rn(A2, A3));
        const float S   = __fadd_rn(z2, e2);
        const float d   = __fsub_rn(S, __fmul_rn(2.0f, dot));

        const u32 db = __float_as_uint(d);
        const u32 kd = (db & 0x80000000u) ? ~db : (db | 0x80000000u);
        const unsigned long long pk = (((unsigned long long)kd) << 24) | (unsigned long long)col;
        atomicMin(rowBest + row, pk);   // fp32-equal d -> smaller col = numpy first-index
    }
}

__global__ void k_ids(const unsigned long long* __restrict__ rowBest,
                      float* __restrict__ outIds) {
    int n = blockIdx.x * 256 + threadIdx.x;
    if (n < NN) outIds[n] = (float)((int)(rowBest[n] & 0xFFFFFFULL) & (KK - 1));
}

// Coalesced z_q gather: block = (64-hw tile, b, c-half). Stage the 64 needed
// emb rows (one 128-col half) in LDS [64][129] (pad -> conflict-free column
// reads), coalesced global reads; write out[b][c][hw0..hw0+63] as 256B runs.
// Fused fp64 loss.
__global__ __launch_bounds__(256)
void k_gather(const float* __restrict__ z, const float* __restrict__ emb,
              const unsigned long long* __restrict__ rowBest,
              float* __restrict__ outZq, double* __restrict__ lossSum) {
    __shared__ float lt[64][129];
    __shared__ u32 idr[64];
    __shared__ double red[4];
    const int t = threadIdx.x;
    const int hw0 = blockIdx.x * 64, b = blockIdx.y;
    const int h2 = blockIdx.z;                // channel half 0/1
    const int w = t >> 6, l = t & 63;

    if (t < 64)
        idr[t] = (u32)(rowBest[b * HWD + hw0 + t] & 0xFFFFFFULL) & (KK - 1);
    __syncthreads();

    const int rr = t >> 7, cc = t & 127;
    for (int s = 0; s < 32; ++s) {
        const int r = s * 2 + rr;
        lt[r][cc] = emb[(size_t)idr[r] * DD + h2 * 128 + cc];
    }
    __syncthreads();

    double lsum = 0.0;
#pragma unroll
    for (int i = 0; i < 32; ++i) {
        const int cl = i * 4 + w;
        const int c  = h2 * 128 + cl;
        const size_t f = ((size_t)(b * CC + c)) * HWD + hw0 + l;
        const float zq = lt[l][cl];
        const float zv = z[f];
        outZq[f] = zq;
        const double dif = (double)zq - (double)zv;
        lsum += dif * dif;
    }
#pragma unroll
    for (int o = 32; o; o >>= 1) lsum += __shfl_down(lsum, o);
    if (l == 0) red[w] = lsum;
    __syncthreads();
    if (t == 0) atomicAdd(lossSum, red[0] + red[1] + red[2] + red[3]);
}

__global__ void k_loss(const double* __restrict__ lossSum, float* __restrict__ outLoss) {
    double m = *lossSum / (double)ZQ_N;
    outLoss[0] = (float)(1.25 * m);   // loss = commitment + codebook
    outLoss[1] = (float)(0.25 * m);   // commitment (cost 0.25)
    outLoss[2] = (float)m;            // codebook
}

extern "C" void kernel_launch(void* const* d_in, const int* in_sizes, int n_in,
                              void* d_out, int out_size, void* d_ws, size_t ws_size,
                              hipStream_t stream) {
    const float* z   = (const float*)d_in[0];
    const float* emb = (const float*)d_in[1];
    float* out = (float*)d_out;
    char* ws = (char*)d_ws;

    if (ws_size < (size_t)WS_NEEDED) return;

    unsigned long long* rowBest = (unsigned long long*)(ws + WS_ROWBEST);
    double*             lossSum = (double*)(ws + WS_LOSS);
    u16*   zb     = (u16*)(out + ZB_OFF);
    u16*   eb     = (u16*)(out + EB_OFF);
    uint2* queue  = (uint2*)(out + Q_OFF);
    u32*   segCnt = (u32*)(out + SEGCNT_OFF);
    u32*   bestC  = (u32*)(out + BC_OFF);

    hipLaunchKernelGGL(k_init,    dim3(64),          dim3(256), 0, stream, rowBest, lossSum, bestC, segCnt);
    hipLaunchKernelGGL(k_cvt_z,   dim3(16, 4, 16),   dim3(256), 0, stream, z, zb);
    hipLaunchKernelGGL(k_cvt_e,   dim3(2048),        dim3(256), 0, stream, emb, eb);
    hipLaunchKernelGGL(k_gemm,    dim3(8192),        dim3(256), 0, stream, zb, eb, bestC, segCnt, queue);
    hipLaunchKernelGGL(k_rescore, dim3(512),         dim3(512), 0, stream, z, emb, queue, segCnt, bestC, rowBest);
    hipLaunchKernelGGL(k_ids,     dim3(64),          dim3(256), 0, stream, rowBest, out + ZQ_N + 3);
    hipLaunchKernelGGL(k_gather,  dim3(16, 16, 2),   dim3(256), 0, stream, z, emb, rowBest, out, lossSum);
    hipLaunchKernelGGL(k_loss,    dim3(1),           dim3(1),   0, stream, lossSum, out + ZQ_N);
}

// Round 8
// 246.929 us; speedup vs baseline: 3.8174x; 1.4096x over previous
//
#include <hip/hip_runtime.h>

// Problem constants
#define BB    16
#define CC    256               // channels == embed dim
#define HWD   1024              // 32*32
#define NN    16384             // BB*HWD rows
#define KK    8192              // codebook size
#define DD    256               // embed dim
#define ZQ_N  4194304           // BB*CC*HWD output elements

// Workspace layout (bytes) -- TOTAL 131,080 B (proven)
#define WS_ROWBEST 0            // u64 rowBest[NN]   131,072 B
#define WS_LOSS    131072       // double lossSum          8 B
#define WS_NEEDED  131080

// Scratch inside d_out (float-index units). out_size = 4,210,691 floats.
#define ZB_OFF      0           // ushort zb[NN*DD]     floats [0 .. 2,097,152)
#define EB_OFF      2097152     // ushort eb[KK*DD]     floats [.. 3,145,728)
#define Q_OFF       3145728     // uint2 queue[128][SEGCAP]  (1,046,528 u32)
#define SEGCNT_OFF  4192256     // u32 segCnt[128]
#define BC_OFF      4194304     // u32 bestC[NN]        floats [.. 4,210,688)
#define SEGCAP      4088u       // entries per row-block segment (8B each)
#define LQCAP       768         // per-block LDS candidate list (exact overflow fallback)

#define CMARGIN  4e-4f   // >= 2*eps_tot (bf16 dot ~1e-4 + numpy-vs-coarse ~6.5e-5 + e2-omit 4e-6)

typedef short short8 __attribute__((ext_vector_type(8)));
typedef float f32x4  __attribute__((ext_vector_type(4)));
typedef unsigned short u16;
typedef unsigned int   u32;

// ---- helpers ----
static __device__ __forceinline__ u32 cenc(float x) {   // sortable f32
    u32 u = __float_as_uint(x);
    return (u & 0x80000000u) ? ~u : (u | 0x80000000u);
}
static __device__ __forceinline__ float cdec(u32 k) {
    u32 u = (k & 0x80000000u) ? (k ^ 0x80000000u) : ~k;
    return __uint_as_float(u);
}
static __device__ __forceinline__ u16 f2bf(float f) {    // RNE f32->bf16
    u32 u = __float_as_uint(f);
    return (u16)((u + 0x7FFFu + ((u >> 16) & 1u)) >> 16);
}

// Fused prologue: blocks [0,1024) = cvt_z, [1024,3072) = cvt_e, [3072,3136) = init.
// All three are independent -> one launch instead of three (kills 2 launch gaps).
__global__ __launch_bounds__(256)
void k_prep(const float* __restrict__ z, const float* __restrict__ emb,
            u16* __restrict__ zb, u16* __restrict__ eb,
            unsigned long long* __restrict__ rowBest, double* __restrict__ lossSum,
            u32* __restrict__ bestC, u32* __restrict__ segCnt) {
    __shared__ float tile[64][65];
    const int bid = blockIdx.x;
    const int t = threadIdx.x;
    if (bid < 1024) {
        // ---- cvt_z: z [b][d][hw] f32 -> zb16T [b*1024+hw][d] bf16 ----
        const int b = bid >> 6, d0 = ((bid >> 4) & 3) * 64, h0 = (bid & 15) * 64;
        const float* zp = z + ((size_t)b * CC + d0) * HWD + h0;
#pragma unroll
        for (int i = 0; i < 4; ++i) {
            int fid = i * 256 + t;
            int dd = fid >> 4, hq = (fid & 15) * 4;
            float4 v = *(const float4*)(zp + (size_t)dd * HWD + hq);
            tile[dd][hq] = v.x; tile[dd][hq + 1] = v.y; tile[dd][hq + 2] = v.z; tile[dd][hq + 3] = v.w;
        }
        __syncthreads();
        u16* op = zb + ((size_t)b * HWD + h0) * DD + d0;
#pragma unroll
        for (int i = 0; i < 4; ++i) {
            int fid = i * 256 + t;
            int hh = fid >> 4, dq = (fid & 15) * 4;
            ushort4 o;
            o.x = f2bf(tile[dq + 0][hh]); o.y = f2bf(tile[dq + 1][hh]);
            o.z = f2bf(tile[dq + 2][hh]); o.w = f2bf(tile[dq + 3][hh]);
            *(ushort4*)(op + (size_t)hh * DD + dq) = o;
        }
    } else if (bid < 3072) {
        // ---- cvt_e: emb f32 -> bf16 stream ----
        int i = (bid - 1024) * 256 + t;
        float4 v = ((const float4*)emb)[i];
        ushort4 o;
        o.x = f2bf(v.x); o.y = f2bf(v.y); o.z = f2bf(v.z); o.w = f2bf(v.w);
        ((ushort4*)eb)[i] = o;
    } else {
        // ---- init ----
        int i = (bid - 3072) * 256 + t;
        if (i < NN) {
            rowBest[i] = (((unsigned long long)0xFF800000u) << 24) | 0xFFFFFFULL; // +inf key
            bestC[i]   = 0xFFFFFFFFu;   // decodes NaN; all bound math NaN-safe (fminf)
        }
        if (i < 128) segCnt[i] = 0u;
        if (i == 128) *lossSum = 0.0;
    }
}

#define VMW8()  asm volatile("s_waitcnt vmcnt(8)"  ::: "memory")
#define VMW4()  asm volatile("s_waitcnt vmcnt(4)"  ::: "memory")
#define VMW0()  asm volatile("s_waitcnt vmcnt(0)"  ::: "memory")
#define LKW()   asm volatile("s_waitcnt lgkmcnt(0)" ::: "memory")
#define SBAR()  __builtin_amdgcn_s_barrier()

// bf16 MFMA coarse GEMM, 128x128 tile, 4 waves, BK=32, 8 phases,
// 3-deep counted-vmcnt pipeline (r3-proven, 176us).  Epilogue change vs r3:
// the candidate scan is gated per (mi,r) by the pre-shuffle ni-max (fmx) --
// -2*fmx is exactly min-over-ni of s, so the gate is lossless and prunes the
// common path from 64 predicated checks to 16 gates per thread.
__global__ __launch_bounds__(256, 3)
void k_gemm(const u16* __restrict__ zb, const u16* __restrict__ eb,
            u32* __restrict__ bestC, u32* __restrict__ segCnt, uint2* __restrict__ queue) {
    // 3 buffers x (A 8KB + B 8KB) = 48KB
    __shared__ __align__(16) char smem[49152];
    __shared__ u32 lqn, qbase;

    // Supertile XCD swizzle: XCD x owns col-tiles [8x,8x+8); row-tiles in
    // supertiles of 16 -> L2 working set ~1MB A + 0.5MB B.
    const int bid = blockIdx.x;
    const int xcd = bid & 7, idx = bid >> 3;
    const int bx = (idx >> 7) * 16 + (idx & 15);
    const int by = xcd * 8 + ((idx >> 4) & 7);
    const int row0 = bx * 128, col0 = by * 128;

    const int t = threadIdx.x;
    const int wid = t >> 6, l = t & 63;
    const int wy = wid >> 1, wx = wid & 1;    // wave grid 2x2, each wave 64x64 out

    f32x4 acc[4][4];
#pragma unroll
    for (int mi = 0; mi < 4; ++mi)
#pragma unroll
        for (int ni = 0; ni < 4; ++ni) acc[mi][ni] = (f32x4){0.f, 0.f, 0.f, 0.f};

    const int rbase = wid * 32;                       // this wave's staging rows
    // Stage: 64B rows; LDS[r][c] holds global chunk c ^ ((r>>1)&3).
    const int srow   = l >> 2;
    const int schunk = (l & 3) ^ ((l >> 3) & 3);      // lane-constant
    // Read: chunk g=(l>>4) of row base+(l&15) lives at ((l>>4)^((l>>1)&3))<<4
    const int rchunk = (((l >> 4) ^ ((l >> 1) & 3)) << 4);
    const int rrow   = l & 15;

    auto stage = [&](int buf, int kc) {
        char* As = smem + buf * 16384;
        char* Bs = As + 8192;
#pragma unroll
        for (int j = 0; j < 2; ++j) {                 // 16 rows per instr
            const int rl = rbase + j * 16 + srow;
            const u16* gA = zb + (size_t)(row0 + rl) * DD + kc + schunk * 8;
            const u16* gB = eb + (size_t)(col0 + rl) * DD + kc + schunk * 8;
            __builtin_amdgcn_global_load_lds(
                (const __attribute__((address_space(1))) u32*)gA,
                (__attribute__((address_space(3))) u32*)(As + (rbase + j * 16) * 64), 16, 0, 0);
            __builtin_amdgcn_global_load_lds(
                (const __attribute__((address_space(1))) u32*)gB,
                (__attribute__((address_space(3))) u32*)(Bs + (rbase + j * 16) * 64), 16, 0, 0);
        }
    };

    auto compute = [&](int buf) {
        const char* As = smem + buf * 16384;
        const char* Bs = As + 8192;
        short8 a[4], b[4];
#pragma unroll
        for (int mi = 0; mi < 4; ++mi)
            a[mi] = *(const short8*)(As + (wy * 64 + mi * 16 + rrow) * 64 + rchunk);
#pragma unroll
        for (int ni = 0; ni < 4; ++ni)
            b[ni] = *(const short8*)(Bs + (wx * 64 + ni * 16 + rrow) * 64 + rchunk);
        __builtin_amdgcn_s_setprio(1);
#pragma unroll
        for (int mi = 0; mi < 4; ++mi)
#pragma unroll
            for (int ni = 0; ni < 4; ++ni)
                acc[mi][ni] = __builtin_amdgcn_mfma_f32_16x16x32_bf16(a[mi], b[ni], acc[mi][ni], 0, 0, 0);
        __builtin_amdgcn_s_setprio(0);
    };

    // prologue: 3 tiles in flight (12 loads/wave)
    stage(0, 0); stage(1, 32); stage(2, 64);
    // 8 phases; vmcnt never drains to 0 until the last tile
    VMW8(); SBAR(); compute(0); LKW(); SBAR(); stage(0, 96);
    VMW8(); SBAR(); compute(1); LKW(); SBAR(); stage(1, 128);
    VMW8(); SBAR(); compute(2); LKW(); SBAR(); stage(2, 160);
    VMW8(); SBAR(); compute(0); LKW(); SBAR(); stage(0, 192);
    VMW8(); SBAR(); compute(1); LKW(); SBAR(); stage(1, 224);
    VMW8(); SBAR(); compute(2);
    VMW4(); SBAR(); compute(0);
    VMW0(); SBAR(); compute(1);

    // ---- epilogue: scratch aliases buffer 0 (phase-7 barrier fenced) ----
    float* rm = (float*)smem;                   // [128][2] row-min, then fresh bound
    u32* lqe  = (u32*)(smem + 1024);            // candidate entries (3KB)
    u32* lqs  = lqe + LQCAP;                    // candidate scores  (3KB) ends @7168

    // per-row coarse min (= -2 * max dot); keep pre-shuffle ni-max for gating
    float fmx[4][4];
#pragma unroll
    for (int mi = 0; mi < 4; ++mi)
#pragma unroll
        for (int r = 0; r < 4; ++r) {
            float v = fmaxf(fmaxf(acc[mi][0][r], acc[mi][1][r]), fmaxf(acc[mi][2][r], acc[mi][3][r]));
            fmx[mi][r] = v;                      // max over this lane's 4 ni
            v = fmaxf(v, __shfl_xor(v, 1));
            v = fmaxf(v, __shfl_xor(v, 2));
            v = fmaxf(v, __shfl_xor(v, 4));
            v = fmaxf(v, __shfl_xor(v, 8));
            if ((l & 15) == 0)
                rm[(wy * 64 + mi * 16 + ((l >> 4) << 2) + r) * 2 + wx] = -2.0f * v;
        }
    __syncthreads();

    // fresh per-row bound: ONE coalesced returning atomicMin per row per block
    if (t < 128) {
        float mn = fminf(rm[t * 2], rm[t * 2 + 1]);
        u32 old = atomicMin(bestC + row0 + t, cenc(mn));
        rm[t * 2] = fminf(mn, cdec(old));   // NaN-safe: fminf(x, NaN) = x
    }
    if (t == 0) lqn = 0;
    __syncthreads();

    uint2* qseg = queue + (size_t)bx * SEGCAP;

    // candidates (+scores) -> LDS list; exact overflow -> direct global slot
#pragma unroll
    for (int mi = 0; mi < 4; ++mi)
#pragma unroll
        for (int r = 0; r < 4; ++r) {
            const int rl = wy * 64 + mi * 16 + ((l >> 4) << 2) + r;
            const float cut = rm[rl * 2] + CMARGIN;
            if (-2.0f * fmx[mi][r] > cut) continue;   // lossless gate: min_ni(s) > cut
            const int row = row0 + rl;
#pragma unroll
            for (int ni = 0; ni < 4; ++ni) {
                const float s = -2.0f * acc[mi][ni][r];
                if (s <= cut) {
                    const int col = col0 + wx * 64 + ni * 16 + (l & 15);
                    u32 li = atomicAdd(&lqn, 1u);
                    if (li < LQCAP) {
                        lqe[li] = ((u32)row << 13) | (u32)col;
                        lqs[li] = __float_as_uint(s);
                    } else {
                        u32 gi = atomicAdd(segCnt + bx, 1u);   // rare exact fallback
                        if (gi < SEGCAP)
                            qseg[gi] = make_uint2(((u32)row << 13) | (u32)col, __float_as_uint(s));
                    }
                }
            }
        }
    __syncthreads();
    if (t == 0) {
        u32 n = min(lqn, (u32)LQCAP);
        lqn = n;
        qbase = atomicAdd(segCnt + bx, n);  // single reservation into row-block segment
    }
    __syncthreads();
    for (u32 i2 = t; i2 < lqn; i2 += 256) {
        u32 gi = qbase + i2;
        if (gi < SEGCAP) qseg[gi] = make_uint2(lqe[i2], lqs[i2]);
    }
}

// Four blocks per row-block segment (interleaved entries): survivors share a
// 128-row z window -> L2-reused strided reads.
// Filter by stored coarse score vs final bestC; numpy-fp32 replica on survivors.
__global__ __launch_bounds__(512)
void k_rescore(const float* __restrict__ z, const float* __restrict__ emb,
               const uint2* __restrict__ queue, const u32* __restrict__ segCnt,
               const u32* __restrict__ bestC,
               unsigned long long* __restrict__ rowBest) {
    const int seg = blockIdx.x >> 2;
    const int part = blockIdx.x & 3;
    const u32 n = min(segCnt[seg], SEGCAP);
    const uint2* q = queue + (size_t)seg * SEGCAP;
    for (u32 i = part * 512 + threadIdx.x; i < n; i += 2048) {
        const uint2 ent = q[i];
        const int row = (int)(ent.x >> 13), col = (int)(ent.x & 8191u);
        const float s = __uint_as_float(ent.y);
        const float bound = cdec(bestC[row]);      // final global coarse min (finite)
        if (s > bound + CMARGIN) continue;

        // ---- bit-exact numpy fp32 replica (validated rounds 5-8) ----
        const int b = row >> 10, hw = row & 1023;
        const float* zr = z + (size_t)b * CC * HWD + hw;   // element d at zr[d*HWD]
        const float* er = emb + (size_t)col * DD;

        float A0 = 0.f, A1 = 0.f, A2 = 0.f, A3 = 0.f;
        float zh0 = 0.f, eh0 = 0.f, z2 = 0.f, e2 = 0.f;
#pragma unroll
        for (int h = 0; h < 2; ++h) {
            const int base = h * 128;
            float zv[8], ev[8], rz[8], re[8];
#pragma unroll
            for (int q2 = 0; q2 < 8; ++q2) { zv[q2] = zr[(size_t)(base + q2) * HWD]; ev[q2] = er[base + q2]; }
#pragma unroll
            for (int q2 = 0; q2 < 8; ++q2) { rz[q2] = __fmul_rn(zv[q2], zv[q2]); re[q2] = __fmul_rn(ev[q2], ev[q2]); }
            A0 = __fadd_rn(A0, __fmul_rn(zv[0], ev[0])); A1 = __fadd_rn(A1, __fmul_rn(zv[1], ev[1]));
            A2 = __fadd_rn(A2, __fmul_rn(zv[2], ev[2])); A3 = __fadd_rn(A3, __fmul_rn(zv[3], ev[3]));
            A0 = __fadd_rn(A0, __fmul_rn(zv[4], ev[4])); A1 = __fadd_rn(A1, __fmul_rn(zv[5], ev[5]));
            A2 = __fadd_rn(A2, __fmul_rn(zv[6], ev[6])); A3 = __fadd_rn(A3, __fmul_rn(zv[7], ev[7]));
            for (int i2 = 8; i2 < 128; i2 += 8) {
#pragma unroll
                for (int q2 = 0; q2 < 8; ++q2) { zv[q2] = zr[(size_t)(base + i2 + q2) * HWD]; ev[q2] = er[base + i2 + q2]; }
#pragma unroll
                for (int q2 = 0; q2 < 8; ++q2) {
                    rz[q2] = __fadd_rn(rz[q2], __fmul_rn(zv[q2], zv[q2]));
                    re[q2] = __fadd_rn(re[q2], __fmul_rn(ev[q2], ev[q2]));
                }
                A0 = __fadd_rn(A0, __fmul_rn(zv[0], ev[0])); A1 = __fadd_rn(A1, __fmul_rn(zv[1], ev[1]));
                A2 = __fadd_rn(A2, __fmul_rn(zv[2], ev[2])); A3 = __fadd_rn(A3, __fmul_rn(zv[3], ev[3]));
                A0 = __fadd_rn(A0, __fmul_rn(zv[4], ev[4])); A1 = __fadd_rn(A1, __fmul_rn(zv[5], ev[5]));
                A2 = __fadd_rn(A2, __fmul_rn(zv[6], ev[6])); A3 = __fadd_rn(A3, __fmul_rn(zv[7], ev[7]));
            }
            float cz = __fadd_rn(__fadd_rn(__fadd_rn(rz[0], rz[1]), __fadd_rn(rz[2], rz[3])),
                                 __fadd_rn(__fadd_rn(rz[4], rz[5]), __fadd_rn(rz[6], rz[7])));
            float ce = __fadd_rn(__fadd_rn(__fadd_rn(re[0], re[1]), __fadd_rn(re[2], re[3])),
                                 __fadd_rn(__fadd_rn(re[4], re[5]), __fadd_rn(re[6], re[7])));
            if (h == 0) { zh0 = cz; eh0 = ce; }
            else        { z2 = __fadd_rn(zh0, cz); e2 = __fadd_rn(eh0, ce); }
        }
        const float dot = __fadd_rn(__fadd_rn(A0, A1), __fadd_rn(A2, A3));
        const float S   = __fadd_rn(z2, e2);
        const float d   = __fsub_rn(S, __fmul_rn(2.0f, dot));

        const u32 db = __float_as_uint(d);
        const u32 kd = (db & 0x80000000u) ? ~db : (db | 0x80000000u);
        const unsigned long long pk = (((unsigned long long)kd) << 24) | (unsigned long long)col;
        atomicMin(rowBest + row, pk);   // fp32-equal d -> smaller col = numpy first-index
    }
}

// Fused gather + ids.  Block = (64-hw tile, b, c-half).  h2==0 blocks also
// emit the ids output from the already-loaded idr[] (same write pattern as the
// old k_ids: each address has exactly one writer).  Fused fp64 loss partial.
__global__ __launch_bounds__(256)
void k_gather(const float* __restrict__ z, const float* __restrict__ emb,
              const unsigned long long* __restrict__ rowBest,
              float* __restrict__ outZq, double* __restrict__ lossSum,
              float* __restrict__ outIds) {   // outIds = out + ZQ_N + 3
    __shared__ float lt[64][129];
    __shared__ u32 idr[64];
    __shared__ double red[4];
    const int t = threadIdx.x;
    const int hw0 = blockIdx.x * 64, b = blockIdx.y;
    const int h2 = blockIdx.z;                // channel half 0/1
    const int w = t >> 6, l = t & 63;

    if (t < 64) {
        u32 id = (u32)(rowBest[b * HWD + hw0 + t] & 0xFFFFFFULL) & (KK - 1);
        idr[t] = id;
        if (h2 == 0) outIds[b * HWD + hw0 + t] = (float)id;   // ids output
    }
    __syncthreads();

    const int rr = t >> 7, cc = t & 127;
    for (int s = 0; s < 32; ++s) {
        const int r = s * 2 + rr;
        lt[r][cc] = emb[(size_t)idr[r] * DD + h2 * 128 + cc];
    }
    __syncthreads();

    double lsum = 0.0;
#pragma unroll
    for (int i = 0; i < 32; ++i) {
        const int cl = i * 4 + w;
        const int c  = h2 * 128 + cl;
        const size_t f = ((size_t)(b * CC + c)) * HWD + hw0 + l;
        const float zq = lt[l][cl];
        const float zv = z[f];
        outZq[f] = zq;
        const double dif = (double)zq - (double)zv;
        lsum += dif * dif;
    }
#pragma unroll
    for (int o = 32; o; o >>= 1) lsum += __shfl_down(lsum, o);
    if (l == 0) red[w] = lsum;
    __syncthreads();
    if (t == 0) atomicAdd(lossSum, red[0] + red[1] + red[2] + red[3]);
}

__global__ void k_loss(const double* __restrict__ lossSum, float* __restrict__ outLoss) {
    double m = *lossSum / (double)ZQ_N;
    outLoss[0] = (float)(1.25 * m);   // loss = commitment + codebook
    outLoss[1] = (float)(0.25 * m);   // commitment (cost 0.25)
    outLoss[2] = (float)m;            // codebook
}

extern "C" void kernel_launch(void* const* d_in, const int* in_sizes, int n_in,
                              void* d_out, int out_size, void* d_ws, size_t ws_size,
                              hipStream_t stream) {
    const float* z   = (const float*)d_in[0];
    const float* emb = (const float*)d_in[1];
    float* out = (float*)d_out;
    char* ws = (char*)d_ws;

    if (ws_size < (size_t)WS_NEEDED) return;

    unsigned long long* rowBest = (unsigned long long*)(ws + WS_ROWBEST);
    double*             lossSum = (double*)(ws + WS_LOSS);
    u16*   zb     = (u16*)(out + ZB_OFF);
    u16*   eb     = (u16*)(out + EB_OFF);
    uint2* queue  = (uint2*)(out + Q_OFF);
    u32*   segCnt = (u32*)(out + SEGCNT_OFF);
    u32*   bestC  = (u32*)(out + BC_OFF);

    hipLaunchKernelGGL(k_prep,    dim3(3136),        dim3(256), 0, stream,
                       z, emb, zb, eb, rowBest, lossSum, bestC, segCnt);
    hipLaunchKernelGGL(k_gemm,    dim3(8192),        dim3(256), 0, stream, zb, eb, bestC, segCnt, queue);
    hipLaunchKernelGGL(k_rescore, dim3(512),         dim3(512), 0, stream, z, emb, queue, segCnt, bestC, rowBest);
    hipLaunchKernelGGL(k_gather,  dim3(16, 16, 2),   dim3(256), 0, stream,
                       z, emb, rowBest, out, lossSum, out + ZQ_N + 3);
    hipLaunchKernelGGL(k_loss,    dim3(1),           dim3(1),   0, stream, lossSum, out + ZQ_N);
}

// Round 9
// 199.468 us; speedup vs baseline: 4.7257x; 1.2379x over previous
//
#include <hip/hip_runtime.h>

// Problem constants
#define BB    16
#define CC    256               // channels == embed dim
#define HWD   1024              // 32*32
#define NN    16384             // BB*HWD rows
#define KK    8192              // codebook size
#define DD    256               // embed dim
#define ZQ_N  4194304           // BB*CC*HWD output elements

// Workspace layout (bytes) -- TOTAL 131,080 B (proven)
#define WS_ROWBEST 0            // u64 rowBest[NN]   131,072 B
#define WS_LOSS    131072       // double lossSum          8 B
#define WS_NEEDED  131080

// Scratch inside d_out (float-index units). out_size = 4,210,691 floats.
#define ZB_OFF      0           // ushort zb[NN*DD]     floats [0 .. 2,097,152)
#define EB_OFF      2097152     // ushort eb[KK*DD]     floats [.. 3,145,728)
#define Q_OFF       3145728     // uint2 queue[128][SEGCAP]  (1,046,528 u32)
#define SEGCNT_OFF  4192256     // u32 segCnt[128]
#define BC_OFF      4194304     // u32 bestC[NN]        floats [.. 4,210,688)
#define SEGCAP      4088u       // entries per row-block segment (8B each)
#define LQCAP       768         // per-block LDS candidate list (exact overflow fallback)

#define CMARGIN  4e-4f   // >= 2*eps_tot (bf16 dot ~1e-4 + numpy-vs-coarse ~6.5e-5 + e2-omit 4e-6)

typedef short short8 __attribute__((ext_vector_type(8)));
typedef float f32x4  __attribute__((ext_vector_type(4)));
typedef unsigned short u16;
typedef unsigned int   u32;

// ---- helpers ----
static __device__ __forceinline__ u32 cenc(float x) {   // sortable f32
    u32 u = __float_as_uint(x);
    return (u & 0x80000000u) ? ~u : (u | 0x80000000u);
}
static __device__ __forceinline__ float cdec(u32 k) {
    u32 u = (k & 0x80000000u) ? (k ^ 0x80000000u) : ~k;
    return __uint_as_float(u);
}
static __device__ __forceinline__ u16 f2bf(float f) {    // RNE f32->bf16
    u32 u = __float_as_uint(f);
    return (u16)((u + 0x7FFFu + ((u >> 16) & 1u)) >> 16);
}

// Fused prologue: blocks [0,1024) = cvt_z, [1024,3072) = cvt_e, [3072,3136) = init.
__global__ __launch_bounds__(256)
void k_prep(const float* __restrict__ z, const float* __restrict__ emb,
            u16* __restrict__ zb, u16* __restrict__ eb,
            unsigned long long* __restrict__ rowBest, double* __restrict__ lossSum,
            u32* __restrict__ bestC, u32* __restrict__ segCnt) {
    __shared__ float tile[64][65];
    const int bid = blockIdx.x;
    const int t = threadIdx.x;
    if (bid < 1024) {
        // ---- cvt_z: z [b][d][hw] f32 -> zb16T [b*1024+hw][d] bf16 ----
        const int b = bid >> 6, d0 = ((bid >> 4) & 3) * 64, h0 = (bid & 15) * 64;
        const float* zp = z + ((size_t)b * CC + d0) * HWD + h0;
#pragma unroll
        for (int i = 0; i < 4; ++i) {
            int fid = i * 256 + t;
            int dd = fid >> 4, hq = (fid & 15) * 4;
            float4 v = *(const float4*)(zp + (size_t)dd * HWD + hq);
            tile[dd][hq] = v.x; tile[dd][hq + 1] = v.y; tile[dd][hq + 2] = v.z; tile[dd][hq + 3] = v.w;
        }
        __syncthreads();
        u16* op = zb + ((size_t)b * HWD + h0) * DD + d0;
#pragma unroll
        for (int i = 0; i < 4; ++i) {
            int fid = i * 256 + t;
            int hh = fid >> 4, dq = (fid & 15) * 4;
            ushort4 o;
            o.x = f2bf(tile[dq + 0][hh]); o.y = f2bf(tile[dq + 1][hh]);
            o.z = f2bf(tile[dq + 2][hh]); o.w = f2bf(tile[dq + 3][hh]);
            *(ushort4*)(op + (size_t)hh * DD + dq) = o;
        }
    } else if (bid < 3072) {
        // ---- cvt_e: emb f32 -> bf16 stream ----
        int i = (bid - 1024) * 256 + t;
        float4 v = ((const float4*)emb)[i];
        ushort4 o;
        o.x = f2bf(v.x); o.y = f2bf(v.y); o.z = f2bf(v.z); o.w = f2bf(v.w);
        ((ushort4*)eb)[i] = o;
    } else {
        // ---- init ----
        int i = (bid - 3072) * 256 + t;
        if (i < NN) {
            rowBest[i] = (((unsigned long long)0xFF800000u) << 24) | 0xFFFFFFULL; // +inf key
            bestC[i]   = 0xFFFFFFFFu;   // decodes NaN; all bound math NaN-safe (fminf)
        }
        if (i < 128) segCnt[i] = 0u;
        if (i == 128) *lossSum = 0.0;
    }
}

#define VMW8()  asm volatile("s_waitcnt vmcnt(8)"  ::: "memory")
#define VMW4()  asm volatile("s_waitcnt vmcnt(4)"  ::: "memory")
#define VMW0()  asm volatile("s_waitcnt vmcnt(0)"  ::: "memory")
#define LKW()   asm volatile("s_waitcnt lgkmcnt(0)" ::: "memory")
#define SBAR()  __builtin_amdgcn_s_barrier()

// bf16 MFMA coarse GEMM, 128x128 tile, 4 waves, BK=32, 8 phases,
// 3-deep counted-vmcnt pipeline + fmx-gated candidate scan (r8-proven, 161us).
// FROZEN -- do not touch.
__global__ __launch_bounds__(256, 3)
void k_gemm(const u16* __restrict__ zb, const u16* __restrict__ eb,
            u32* __restrict__ bestC, u32* __restrict__ segCnt, uint2* __restrict__ queue) {
    // 3 buffers x (A 8KB + B 8KB) = 48KB
    __shared__ __align__(16) char smem[49152];
    __shared__ u32 lqn, qbase;

    // Supertile XCD swizzle: XCD x owns col-tiles [8x,8x+8); row-tiles in
    // supertiles of 16 -> L2 working set ~1MB A + 0.5MB B.
    const int bid = blockIdx.x;
    const int xcd = bid & 7, idx = bid >> 3;
    const int bx = (idx >> 7) * 16 + (idx & 15);
    const int by = xcd * 8 + ((idx >> 4) & 7);
    const int row0 = bx * 128, col0 = by * 128;

    const int t = threadIdx.x;
    const int wid = t >> 6, l = t & 63;
    const int wy = wid >> 1, wx = wid & 1;    // wave grid 2x2, each wave 64x64 out

    f32x4 acc[4][4];
#pragma unroll
    for (int mi = 0; mi < 4; ++mi)
#pragma unroll
        for (int ni = 0; ni < 4; ++ni) acc[mi][ni] = (f32x4){0.f, 0.f, 0.f, 0.f};

    const int rbase = wid * 32;                       // this wave's staging rows
    // Stage: 64B rows; LDS[r][c] holds global chunk c ^ ((r>>1)&3).
    const int srow   = l >> 2;
    const int schunk = (l & 3) ^ ((l >> 3) & 3);      // lane-constant
    // Read: chunk g=(l>>4) of row base+(l&15) lives at ((l>>4)^((l>>1)&3))<<4
    const int rchunk = (((l >> 4) ^ ((l >> 1) & 3)) << 4);
    const int rrow   = l & 15;

    auto stage = [&](int buf, int kc) {
        char* As = smem + buf * 16384;
        char* Bs = As + 8192;
#pragma unroll
        for (int j = 0; j < 2; ++j) {                 // 16 rows per instr
            const int rl = rbase + j * 16 + srow;
            const u16* gA = zb + (size_t)(row0 + rl) * DD + kc + schunk * 8;
            const u16* gB = eb + (size_t)(col0 + rl) * DD + kc + schunk * 8;
            __builtin_amdgcn_global_load_lds(
                (const __attribute__((address_space(1))) u32*)gA,
                (__attribute__((address_space(3))) u32*)(As + (rbase + j * 16) * 64), 16, 0, 0);
            __builtin_amdgcn_global_load_lds(
                (const __attribute__((address_space(1))) u32*)gB,
                (__attribute__((address_space(3))) u32*)(Bs + (rbase + j * 16) * 64), 16, 0, 0);
        }
    };

    auto compute = [&](int buf) {
        const char* As = smem + buf * 16384;
        const char* Bs = As + 8192;
        short8 a[4], b[4];
#pragma unroll
        for (int mi = 0; mi < 4; ++mi)
            a[mi] = *(const short8*)(As + (wy * 64 + mi * 16 + rrow) * 64 + rchunk);
#pragma unroll
        for (int ni = 0; ni < 4; ++ni)
            b[ni] = *(const short8*)(Bs + (wx * 64 + ni * 16 + rrow) * 64 + rchunk);
        __builtin_amdgcn_s_setprio(1);
#pragma unroll
        for (int mi = 0; mi < 4; ++mi)
#pragma unroll
            for (int ni = 0; ni < 4; ++ni)
                acc[mi][ni] = __builtin_amdgcn_mfma_f32_16x16x32_bf16(a[mi], b[ni], acc[mi][ni], 0, 0, 0);
        __builtin_amdgcn_s_setprio(0);
    };

    // prologue: 3 tiles in flight (12 loads/wave)
    stage(0, 0); stage(1, 32); stage(2, 64);
    // 8 phases; vmcnt never drains to 0 until the last tile
    VMW8(); SBAR(); compute(0); LKW(); SBAR(); stage(0, 96);
    VMW8(); SBAR(); compute(1); LKW(); SBAR(); stage(1, 128);
    VMW8(); SBAR(); compute(2); LKW(); SBAR(); stage(2, 160);
    VMW8(); SBAR(); compute(0); LKW(); SBAR(); stage(0, 192);
    VMW8(); SBAR(); compute(1); LKW(); SBAR(); stage(1, 224);
    VMW8(); SBAR(); compute(2);
    VMW4(); SBAR(); compute(0);
    VMW0(); SBAR(); compute(1);

    // ---- epilogue: scratch aliases buffer 0 (phase-7 barrier fenced) ----
    float* rm = (float*)smem;                   // [128][2] row-min, then fresh bound
    u32* lqe  = (u32*)(smem + 1024);            // candidate entries (3KB)
    u32* lqs  = lqe + LQCAP;                    // candidate scores  (3KB) ends @7168

    // per-row coarse min (= -2 * max dot); keep pre-shuffle ni-max for gating
    float fmx[4][4];
#pragma unroll
    for (int mi = 0; mi < 4; ++mi)
#pragma unroll
        for (int r = 0; r < 4; ++r) {
            float v = fmaxf(fmaxf(acc[mi][0][r], acc[mi][1][r]), fmaxf(acc[mi][2][r], acc[mi][3][r]));
            fmx[mi][r] = v;                      // max over this lane's 4 ni
            v = fmaxf(v, __shfl_xor(v, 1));
            v = fmaxf(v, __shfl_xor(v, 2));
            v = fmaxf(v, __shfl_xor(v, 4));
            v = fmaxf(v, __shfl_xor(v, 8));
            if ((l & 15) == 0)
                rm[(wy * 64 + mi * 16 + ((l >> 4) << 2) + r) * 2 + wx] = -2.0f * v;
        }
    __syncthreads();

    // fresh per-row bound: ONE coalesced returning atomicMin per row per block
    if (t < 128) {
        float mn = fminf(rm[t * 2], rm[t * 2 + 1]);
        u32 old = atomicMin(bestC + row0 + t, cenc(mn));
        rm[t * 2] = fminf(mn, cdec(old));   // NaN-safe: fminf(x, NaN) = x
    }
    if (t == 0) lqn = 0;
    __syncthreads();

    uint2* qseg = queue + (size_t)bx * SEGCAP;

    // candidates (+scores) -> LDS list; exact overflow -> direct global slot
#pragma unroll
    for (int mi = 0; mi < 4; ++mi)
#pragma unroll
        for (int r = 0; r < 4; ++r) {
            const int rl = wy * 64 + mi * 16 + ((l >> 4) << 2) + r;
            const float cut = rm[rl * 2] + CMARGIN;
            if (-2.0f * fmx[mi][r] > cut) continue;   // lossless gate: min_ni(s) > cut
            const int row = row0 + rl;
#pragma unroll
            for (int ni = 0; ni < 4; ++ni) {
                const float s = -2.0f * acc[mi][ni][r];
                if (s <= cut) {
                    const int col = col0 + wx * 64 + ni * 16 + (l & 15);
                    u32 li = atomicAdd(&lqn, 1u);
                    if (li < LQCAP) {
                        lqe[li] = ((u32)row << 13) | (u32)col;
                        lqs[li] = __float_as_uint(s);
                    } else {
                        u32 gi = atomicAdd(segCnt + bx, 1u);   // rare exact fallback
                        if (gi < SEGCAP)
                            qseg[gi] = make_uint2(((u32)row << 13) | (u32)col, __float_as_uint(s));
                    }
                }
            }
        }
    __syncthreads();
    if (t == 0) {
        u32 n = min(lqn, (u32)LQCAP);
        lqn = n;
        qbase = atomicAdd(segCnt + bx, n);  // single reservation into row-block segment
    }
    __syncthreads();
    for (u32 i2 = t; i2 < lqn; i2 += 256) {
        u32 gi = qbase + i2;
        if (gi < SEGCAP) qseg[gi] = make_uint2(lqe[i2], lqs[i2]);
    }
}

// Row-centric rescore: block = (segment, 64-row half, entry-part).  The block
// stages its 64-row z window in LDS ONCE via coalesced 256B runs (zl[d][r] --
// same f32 bits the old strided path read), then scans the segment's entries,
// filters by row-window + final bestC bound, and runs the bit-exact numpy
// replica reading z from LDS.  Kills the 16x strided-read amplification and
// the per-survivor global latency chain.
__global__ __launch_bounds__(512)
void k_rescore(const float* __restrict__ z, const float* __restrict__ emb,
               const uint2* __restrict__ queue, const u32* __restrict__ segCnt,
               const u32* __restrict__ bestC,
               unsigned long long* __restrict__ rowBest) {
    __shared__ float zl[256][65];              // [d][row-in-window], +1 pad
    const int bid = blockIdx.x;                // 0..511
    const int seg  = bid >> 2;                 // 0..127
    const int half = (bid >> 1) & 1;           // 64-row half of the 128-row segment
    const int part = bid & 1;                  // entry interleave
    const int b = seg >> 3;                    // batch (8 segments per b)
    const int hwstart = ((seg & 7) << 7) + half * 64;
    const int rlo = seg * 128 + half * 64;     // global row window [rlo, rlo+64)

    // stage the 64-row z window: 256 d x 64 hw, coalesced 256B runs
    const float* zsrc = z + (size_t)b * CC * HWD + hwstart;
    const int t = threadIdx.x;
#pragma unroll
    for (int i = 0; i < 32; ++i) {
        int idx = i * 512 + t;                 // 0..16383
        int d = idx >> 6, j = idx & 63;
        zl[d][j] = zsrc[(size_t)d * HWD + j];
    }
    __syncthreads();

    const u32 n = min(segCnt[seg], SEGCAP);
    const uint2* q = queue + (size_t)seg * SEGCAP;
    for (u32 i = part * 512 + t; i < n; i += 1024) {
        const uint2 ent = q[i];
        const int row = (int)(ent.x >> 13);
        const u32 r = (u32)(row - rlo);
        if (r >= 64u) continue;                // other half's row
        const int col = (int)(ent.x & 8191u);
        const float s = __uint_as_float(ent.y);
        const float bound = cdec(bestC[row]);  // final global coarse min (finite)
        if (s > bound + CMARGIN) continue;

        // ---- bit-exact numpy fp32 replica (validated) -- z from LDS ----
        const float* er = emb + (size_t)col * DD;

        float A0 = 0.f, A1 = 0.f, A2 = 0.f, A3 = 0.f;
        float zh0 = 0.f, eh0 = 0.f, z2 = 0.f, e2 = 0.f;
#pragma unroll
        for (int h = 0; h < 2; ++h) {
            const int base = h * 128;
            float zv[8], ev[8], rz[8], re[8];
#pragma unroll
            for (int q2 = 0; q2 < 8; ++q2) { zv[q2] = zl[base + q2][r]; ev[q2] = er[base + q2]; }
#pragma unroll
            for (int q2 = 0; q2 < 8; ++q2) { rz[q2] = __fmul_rn(zv[q2], zv[q2]); re[q2] = __fmul_rn(ev[q2], ev[q2]); }
            A0 = __fadd_rn(A0, __fmul_rn(zv[0], ev[0])); A1 = __fadd_rn(A1, __fmul_rn(zv[1], ev[1]));
            A2 = __fadd_rn(A2, __fmul_rn(zv[2], ev[2])); A3 = __fadd_rn(A3, __fmul_rn(zv[3], ev[3]));
            A0 = __fadd_rn(A0, __fmul_rn(zv[4], ev[4])); A1 = __fadd_rn(A1, __fmul_rn(zv[5], ev[5]));
            A2 = __fadd_rn(A2, __fmul_rn(zv[6], ev[6])); A3 = __fadd_rn(A3, __fmul_rn(zv[7], ev[7]));
            for (int i2 = 8; i2 < 128; i2 += 8) {
#pragma unroll
                for (int q2 = 0; q2 < 8; ++q2) { zv[q2] = zl[base + i2 + q2][r]; ev[q2] = er[base + i2 + q2]; }
#pragma unroll
                for (int q2 = 0; q2 < 8; ++q2) {
                    rz[q2] = __fadd_rn(rz[q2], __fmul_rn(zv[q2], zv[q2]));
                    re[q2] = __fadd_rn(re[q2], __fmul_rn(ev[q2], ev[q2]));
                }
                A0 = __fadd_rn(A0, __fmul_rn(zv[0], ev[0])); A1 = __fadd_rn(A1, __fmul_rn(zv[1], ev[1]));
                A2 = __fadd_rn(A2, __fmul_rn(zv[2], ev[2])); A3 = __fadd_rn(A3, __fmul_rn(zv[3], ev[3]));
                A0 = __fadd_rn(A0, __fmul_rn(zv[4], ev[4])); A1 = __fadd_rn(A1, __fmul_rn(zv[5], ev[5]));
                A2 = __fadd_rn(A2, __fmul_rn(zv[6], ev[6])); A3 = __fadd_rn(A3, __fmul_rn(zv[7], ev[7]));
            }
            float cz = __fadd_rn(__fadd_rn(__fadd_rn(rz[0], rz[1]), __fadd_rn(rz[2], rz[3])),
                                 __fadd_rn(__fadd_rn(rz[4], rz[5]), __fadd_rn(rz[6], rz[7])));
            float ce = __fadd_rn(__fadd_rn(__fadd_rn(re[0], re[1]), __fadd_rn(re[2], re[3])),
                                 __fadd_rn(__fadd_rn(re[4], re[5]), __fadd_rn(re[6], re[7])));
            if (h == 0) { zh0 = cz; eh0 = ce; }
            else        { z2 = __fadd_rn(zh0, cz); e2 = __fadd_rn(eh0, ce); }
        }
        const float dot = __fadd_rn(__fadd_rn(A0, A1), __fadd_rn(A2, A3));
        const float S   = __fadd_rn(z2, e2);
        const float d   = __fsub_rn(S, __fmul_rn(2.0f, dot));

        const u32 db = __float_as_uint(d);
        const u32 kd = (db & 0x80000000u) ? ~db : (db | 0x80000000u);
        const unsigned long long pk = (((unsigned long long)kd) << 24) | (unsigned long long)col;
        atomicMin(rowBest + row, pk);   // fp32-equal d -> smaller col = numpy first-index
    }
}

// Fused gather + ids.  Block = (64-hw tile, b, c-half).  h2==0 blocks also
// emit the ids output from the already-loaded idr[].  Fused fp64 loss partial.
__global__ __launch_bounds__(256)
void k_gather(const float* __restrict__ z, const float* __restrict__ emb,
              const unsigned long long* __restrict__ rowBest,
              float* __restrict__ outZq, double* __restrict__ lossSum,
              float* __restrict__ outIds) {   // outIds = out + ZQ_N + 3
    __shared__ float lt[64][129];
    __shared__ u32 idr[64];
    __shared__ double red[4];
    const int t = threadIdx.x;
    const int hw0 = blockIdx.x * 64, b = blockIdx.y;
    const int h2 = blockIdx.z;                // channel half 0/1
    const int w = t >> 6, l = t & 63;

    if (t < 64) {
        u32 id = (u32)(rowBest[b * HWD + hw0 + t] & 0xFFFFFFULL) & (KK - 1);
        idr[t] = id;
        if (h2 == 0) outIds[b * HWD + hw0 + t] = (float)id;   // ids output
    }
    __syncthreads();

    const int rr = t >> 7, cc = t & 127;
    for (int s = 0; s < 32; ++s) {
        const int r = s * 2 + rr;
        lt[r][cc] = emb[(size_t)idr[r] * DD + h2 * 128 + cc];
    }
    __syncthreads();

    double lsum = 0.0;
#pragma unroll
    for (int i = 0; i < 32; ++i) {
        const int cl = i * 4 + w;
        const int c  = h2 * 128 + cl;
        const size_t f = ((size_t)(b * CC + c)) * HWD + hw0 + l;
        const float zq = lt[l][cl];
        const float zv = z[f];
        outZq[f] = zq;
        const double dif = (double)zq - (double)zv;
        lsum += dif * dif;
    }
#pragma unroll
    for (int o = 32; o; o >>= 1) lsum += __shfl_down(lsum, o);
    if (l == 0) red[w] = lsum;
    __syncthreads();
    if (t == 0) atomicAdd(lossSum, red[0] + red[1] + red[2] + red[3]);
}

__global__ void k_loss(const double* __restrict__ lossSum, float* __restrict__ outLoss) {
    double m = *lossSum / (double)ZQ_N;
    outLoss[0] = (float)(1.25 * m);   // loss = commitment + codebook
    outLoss[1] = (float)(0.25 * m);   // commitment (cost 0.25)
    outLoss[2] = (float)m;            // codebook
}

extern "C" void kernel_launch(void* const* d_in, const int* in_sizes, int n_in,
                              void* d_out, int out_size, void* d_ws, size_t ws_size,
                              hipStream_t stream) {
    const float* z   = (const float*)d_in[0];
    const float* emb = (const float*)d_in[1];
    float* out = (float*)d_out;
    char* ws = (char*)d_ws;

    if (ws_size < (size_t)WS_NEEDED) return;

    unsigned long long* rowBest = (unsigned long long*)(ws + WS_ROWBEST);
    double*             lossSum = (double*)(ws + WS_LOSS);
    u16*   zb     = (u16*)(out + ZB_OFF);
    u16*   eb     = (u16*)(out + EB_OFF);
    uint2* queue  = (uint2*)(out + Q_OFF);
    u32*   segCnt = (u32*)(out + SEGCNT_OFF);
    u32*   bestC  = (u32*)(out + BC_OFF);

    hipLaunchKernelGGL(k_prep,    dim3(3136),        dim3(256), 0, stream,
                       z, emb, zb, eb, rowBest, lossSum, bestC, segCnt);
    hipLaunchKernelGGL(k_gemm,    dim3(8192),        dim3(256), 0, stream, zb, eb, bestC, segCnt, queue);
    hipLaunchKernelGGL(k_rescore, dim3(512),         dim3(512), 0, stream, z, emb, queue, segCnt, bestC, rowBest);
    hipLaunchKernelGGL(k_gather,  dim3(16, 16, 2),   dim3(256), 0, stream,
                       z, emb, rowBest, out, lossSum, out + ZQ_N + 3);
    hipLaunchKernelGGL(k_loss,    dim3(1),           dim3(1),   0, stream, lossSum, out + ZQ_N);
}

// Round 10
// 186.541 us; speedup vs baseline: 5.0532x; 1.0693x over previous
//
#include <hip/hip_runtime.h>

// Problem constants
#define BB    16
#define CC    256               // channels == embed dim
#define HWD   1024              // 32*32
#define NN    16384             // BB*HWD rows
#define KK    8192              // codebook size
#define DD    256               // embed dim
#define ZQ_N  4194304           // BB*CC*HWD output elements

// Workspace layout (bytes) -- TOTAL 131,080 B (proven)
#define WS_ROWBEST 0            // u64 rowBest[NN]   131,072 B
#define WS_LOSS    131072       // double lossSum          8 B
#define WS_NEEDED  131080

// Scratch inside d_out (float-index units). out_size = 4,210,691 floats.
#define ZB_OFF      0           // ushort zb[NN*DD]     floats [0 .. 2,097,152)
#define EB_OFF      2097152     // ushort eb[KK*DD]     floats [.. 3,145,728)
#define Q_OFF       3145728     // uint2 queue[128][SEGCAP]  (1,046,528 u32)
#define SEGCNT_OFF  4192256     // u32 segCnt[128]
#define BC_OFF      4194304     // u32 bestC[NN]        floats [.. 4,210,688)
#define SEGCAP      4088u       // entries per row-block segment (8B each)
#define LQCAP       768         // per-block LDS candidate list (exact overflow fallback)

#define CMARGIN  4e-4f   // >= 2*eps_tot (bf16 dot ~1e-4 + numpy-vs-coarse ~6.5e-5 + e2-omit 4e-6)

typedef short short8 __attribute__((ext_vector_type(8)));
typedef float f32x4  __attribute__((ext_vector_type(4)));
typedef unsigned short u16;
typedef unsigned int   u32;

// ---- helpers ----
static __device__ __forceinline__ u32 cenc(float x) {   // sortable f32
    u32 u = __float_as_uint(x);
    return (u & 0x80000000u) ? ~u : (u | 0x80000000u);
}
static __device__ __forceinline__ float cdec(u32 k) {
    u32 u = (k & 0x80000000u) ? (k ^ 0x80000000u) : ~k;
    return __uint_as_float(u);
}
static __device__ __forceinline__ u16 f2bf(float f) {    // RNE f32->bf16
    u32 u = __float_as_uint(f);
    return (u16)((u + 0x7FFFu + ((u >> 16) & 1u)) >> 16);
}

// Fused prologue: blocks [0,1024) = cvt_z, [1024,3072) = cvt_e, [3072,3136) = init.
__global__ __launch_bounds__(256)
void k_prep(const float* __restrict__ z, const float* __restrict__ emb,
            u16* __restrict__ zb, u16* __restrict__ eb,
            unsigned long long* __restrict__ rowBest, double* __restrict__ lossSum,
            u32* __restrict__ bestC, u32* __restrict__ segCnt) {
    __shared__ float tile[64][65];
    const int bid = blockIdx.x;
    const int t = threadIdx.x;
    if (bid < 1024) {
        // ---- cvt_z: z [b][d][hw] f32 -> zb16T [b*1024+hw][d] bf16 ----
        const int b = bid >> 6, d0 = ((bid >> 4) & 3) * 64, h0 = (bid & 15) * 64;
        const float* zp = z + ((size_t)b * CC + d0) * HWD + h0;
#pragma unroll
        for (int i = 0; i < 4; ++i) {
            int fid = i * 256 + t;
            int dd = fid >> 4, hq = (fid & 15) * 4;
            float4 v = *(const float4*)(zp + (size_t)dd * HWD + hq);
            tile[dd][hq] = v.x; tile[dd][hq + 1] = v.y; tile[dd][hq + 2] = v.z; tile[dd][hq + 3] = v.w;
        }
        __syncthreads();
        u16* op = zb + ((size_t)b * HWD + h0) * DD + d0;
#pragma unroll
        for (int i = 0; i < 4; ++i) {
            int fid = i * 256 + t;
            int hh = fid >> 4, dq = (fid & 15) * 4;
            ushort4 o;
            o.x = f2bf(tile[dq + 0][hh]); o.y = f2bf(tile[dq + 1][hh]);
            o.z = f2bf(tile[dq + 2][hh]); o.w = f2bf(tile[dq + 3][hh]);
            *(ushort4*)(op + (size_t)hh * DD + dq) = o;
        }
    } else if (bid < 3072) {
        // ---- cvt_e: emb f32 -> bf16 stream ----
        int i = (bid - 1024) * 256 + t;
        float4 v = ((const float4*)emb)[i];
        ushort4 o;
        o.x = f2bf(v.x); o.y = f2bf(v.y); o.z = f2bf(v.z); o.w = f2bf(v.w);
        ((ushort4*)eb)[i] = o;
    } else {
        // ---- init ----
        int i = (bid - 3072) * 256 + t;
        if (i < NN) {
            rowBest[i] = (((unsigned long long)0xFF800000u) << 24) | 0xFFFFFFULL; // +inf key
            bestC[i]   = 0xFFFFFFFFu;   // decodes NaN; all bound math NaN-safe (fminf)
        }
        if (i < 128) segCnt[i] = 0u;
        if (i == 128) *lossSum = 0.0;
    }
}

#define VMW8()  asm volatile("s_waitcnt vmcnt(8)"  ::: "memory")
#define VMW4()  asm volatile("s_waitcnt vmcnt(4)"  ::: "memory")
#define VMW0()  asm volatile("s_waitcnt vmcnt(0)"  ::: "memory")
#define LKW()   asm volatile("s_waitcnt lgkmcnt(0)" ::: "memory")
#define SBAR()  __builtin_amdgcn_s_barrier()

// bf16 MFMA coarse GEMM, 128x128 tile, 4 waves, BK=32, 8 phases,
// 3-deep counted-vmcnt pipeline + fmx-gated candidate scan (r8-proven, 161us).
// r10 change: XCD-LOCAL ROW SWIZZLE -- each XCD owns 16 row-tiles, so the
// epilogue's returning atomicMin(bestC), the segCnt reservation, and the
// queue-segment writes all stay in ONE XCD's L2 (no cross-die atomic
// ping-pong).  Per-XCD L2 working set: 1MB A-slice (resident all kernel) +
// ~192KB sweeping B window.  K-loop byte-identical to r8.
__global__ __launch_bounds__(256, 3)
void k_gemm(const u16* __restrict__ zb, const u16* __restrict__ eb,
            u32* __restrict__ bestC, u32* __restrict__ segCnt, uint2* __restrict__ queue) {
    // 3 buffers x (A 8KB + B 8KB) = 48KB
    __shared__ __align__(16) char smem[49152];
    __shared__ u32 lqn, qbase;

    // XCD-local rows: xcd owns row-tiles [16*xcd, 16*xcd+16); col-tiles sweep
    // sequentially so the concurrent window shares a ~192KB B slice.
    const int bid = blockIdx.x;
    const int xcd = bid & 7, idx = bid >> 3;      // idx 0..1023
    const int bx = xcd * 16 + (idx & 15);         // row-tile 0..127, XCD-local
    const int by = idx >> 4;                      // col-tile 0..63
    const int row0 = bx * 128, col0 = by * 128;

    const int t = threadIdx.x;
    const int wid = t >> 6, l = t & 63;
    const int wy = wid >> 1, wx = wid & 1;    // wave grid 2x2, each wave 64x64 out

    f32x4 acc[4][4];
#pragma unroll
    for (int mi = 0; mi < 4; ++mi)
#pragma unroll
        for (int ni = 0; ni < 4; ++ni) acc[mi][ni] = (f32x4){0.f, 0.f, 0.f, 0.f};

    const int rbase = wid * 32;                       // this wave's staging rows
    // Stage: 64B rows; LDS[r][c] holds global chunk c ^ ((r>>1)&3).
    const int srow   = l >> 2;
    const int schunk = (l & 3) ^ ((l >> 3) & 3);      // lane-constant
    // Read: chunk g=(l>>4) of row base+(l&15) lives at ((l>>4)^((l>>1)&3))<<4
    const int rchunk = (((l >> 4) ^ ((l >> 1) & 3)) << 4);
    const int rrow   = l & 15;

    auto stage = [&](int buf, int kc) {
        char* As = smem + buf * 16384;
        char* Bs = As + 8192;
#pragma unroll
        for (int j = 0; j < 2; ++j) {                 // 16 rows per instr
            const int rl = rbase + j * 16 + srow;
            const u16* gA = zb + (size_t)(row0 + rl) * DD + kc + schunk * 8;
            const u16* gB = eb + (size_t)(col0 + rl) * DD + kc + schunk * 8;
            __builtin_amdgcn_global_load_lds(
                (const __attribute__((address_space(1))) u32*)gA,
                (__attribute__((address_space(3))) u32*)(As + (rbase + j * 16) * 64), 16, 0, 0);
            __builtin_amdgcn_global_load_lds(
                (const __attribute__((address_space(1))) u32*)gB,
                (__attribute__((address_space(3))) u32*)(Bs + (rbase + j * 16) * 64), 16, 0, 0);
        }
    };

    auto compute = [&](int buf) {
        const char* As = smem + buf * 16384;
        const char* Bs = As + 8192;
        short8 a[4], b[4];
#pragma unroll
        for (int mi = 0; mi < 4; ++mi)
            a[mi] = *(const short8*)(As + (wy * 64 + mi * 16 + rrow) * 64 + rchunk);
#pragma unroll
        for (int ni = 0; ni < 4; ++ni)
            b[ni] = *(const short8*)(Bs + (wx * 64 + ni * 16 + rrow) * 64 + rchunk);
        __builtin_amdgcn_s_setprio(1);
#pragma unroll
        for (int mi = 0; mi < 4; ++mi)
#pragma unroll
            for (int ni = 0; ni < 4; ++ni)
                acc[mi][ni] = __builtin_amdgcn_mfma_f32_16x16x32_bf16(a[mi], b[ni], acc[mi][ni], 0, 0, 0);
        __builtin_amdgcn_s_setprio(0);
    };

    // prologue: 3 tiles in flight (12 loads/wave)
    stage(0, 0); stage(1, 32); stage(2, 64);
    // 8 phases; vmcnt never drains to 0 until the last tile
    VMW8(); SBAR(); compute(0); LKW(); SBAR(); stage(0, 96);
    VMW8(); SBAR(); compute(1); LKW(); SBAR(); stage(1, 128);
    VMW8(); SBAR(); compute(2); LKW(); SBAR(); stage(2, 160);
    VMW8(); SBAR(); compute(0); LKW(); SBAR(); stage(0, 192);
    VMW8(); SBAR(); compute(1); LKW(); SBAR(); stage(1, 224);
    VMW8(); SBAR(); compute(2);
    VMW4(); SBAR(); compute(0);
    VMW0(); SBAR(); compute(1);

    // ---- epilogue: scratch aliases buffer 0 (phase-7 barrier fenced) ----
    float* rm = (float*)smem;                   // [128][2] row-min, then fresh bound
    u32* lqe  = (u32*)(smem + 1024);            // candidate entries (3KB)
    u32* lqs  = lqe + LQCAP;                    // candidate scores  (3KB) ends @7168

    // per-row coarse min (= -2 * max dot); keep pre-shuffle ni-max for gating
    float fmx[4][4];
#pragma unroll
    for (int mi = 0; mi < 4; ++mi)
#pragma unroll
        for (int r = 0; r < 4; ++r) {
            float v = fmaxf(fmaxf(acc[mi][0][r], acc[mi][1][r]), fmaxf(acc[mi][2][r], acc[mi][3][r]));
            fmx[mi][r] = v;                      // max over this lane's 4 ni
            v = fmaxf(v, __shfl_xor(v, 1));
            v = fmaxf(v, __shfl_xor(v, 2));
            v = fmaxf(v, __shfl_xor(v, 4));
            v = fmaxf(v, __shfl_xor(v, 8));
            if ((l & 15) == 0)
                rm[(wy * 64 + mi * 16 + ((l >> 4) << 2) + r) * 2 + wx] = -2.0f * v;
        }
    __syncthreads();

    // fresh per-row bound: ONE coalesced returning atomicMin per row per block
    // (bestC lines are XCD-local under the new swizzle -> short RTT)
    if (t < 128) {
        float mn = fminf(rm[t * 2], rm[t * 2 + 1]);
        u32 old = atomicMin(bestC + row0 + t, cenc(mn));
        rm[t * 2] = fminf(mn, cdec(old));   // NaN-safe: fminf(x, NaN) = x
    }
    if (t == 0) lqn = 0;
    __syncthreads();

    uint2* qseg = queue + (size_t)bx * SEGCAP;

    // candidates (+scores) -> LDS list; exact overflow -> direct global slot
#pragma unroll
    for (int mi = 0; mi < 4; ++mi)
#pragma unroll
        for (int r = 0; r < 4; ++r) {
            const int rl = wy * 64 + mi * 16 + ((l >> 4) << 2) + r;
            const float cut = rm[rl * 2] + CMARGIN;
            if (-2.0f * fmx[mi][r] > cut) continue;   // lossless gate: min_ni(s) > cut
            const int row = row0 + rl;
#pragma unroll
            for (int ni = 0; ni < 4; ++ni) {
                const float s = -2.0f * acc[mi][ni][r];
                if (s <= cut) {
                    const int col = col0 + wx * 64 + ni * 16 + (l & 15);
                    u32 li = atomicAdd(&lqn, 1u);
                    if (li < LQCAP) {
                        lqe[li] = ((u32)row << 13) | (u32)col;
                        lqs[li] = __float_as_uint(s);
                    } else {
                        u32 gi = atomicAdd(segCnt + bx, 1u);   // rare exact fallback
                        if (gi < SEGCAP)
                            qseg[gi] = make_uint2(((u32)row << 13) | (u32)col, __float_as_uint(s));
                    }
                }
            }
        }
    __syncthreads();
    if (t == 0) {
        u32 n = min(lqn, (u32)LQCAP);
        lqn = n;
        qbase = atomicAdd(segCnt + bx, n);  // single reservation (XCD-local line)
    }
    __syncthreads();
    for (u32 i2 = t; i2 < lqn; i2 += 256) {
        u32 gi = qbase + i2;
        if (gi < SEGCAP) qseg[gi] = make_uint2(lqe[i2], lqs[i2]);
    }
}

// Row-centric rescore: block = (segment, 64-row half, entry-part).  The block
// stages its 64-row z window in LDS ONCE via coalesced 256B runs (zl[d][r] --
// same f32 bits the old strided path read), then scans the segment's entries,
// filters by row-window + final bestC bound, and runs the bit-exact numpy
// replica reading z from LDS.
__global__ __launch_bounds__(512)
void k_rescore(const float* __restrict__ z, const float* __restrict__ emb,
               const uint2* __restrict__ queue, const u32* __restrict__ segCnt,
               const u32* __restrict__ bestC,
               unsigned long long* __restrict__ rowBest) {
    __shared__ float zl[256][65];              // [d][row-in-window], +1 pad
    const int bid = blockIdx.x;                // 0..511
    const int seg  = bid >> 2;                 // 0..127
    const int half = (bid >> 1) & 1;           // 64-row half of the 128-row segment
    const int part = bid & 1;                  // entry interleave
    const int b = seg >> 3;                    // batch (8 segments per b)
    const int hwstart = ((seg & 7) << 7) + half * 64;
    const int rlo = seg * 128 + half * 64;     // global row window [rlo, rlo+64)

    // stage the 64-row z window: 256 d x 64 hw, coalesced 256B runs
    const float* zsrc = z + (size_t)b * CC * HWD + hwstart;
    const int t = threadIdx.x;
#pragma unroll
    for (int i = 0; i < 32; ++i) {
        int idx = i * 512 + t;                 // 0..16383
        int d = idx >> 6, j = idx & 63;
        zl[d][j] = zsrc[(size_t)d * HWD + j];
    }
    __syncthreads();

    const u32 n = min(segCnt[seg], SEGCAP);
    const uint2* q = queue + (size_t)seg * SEGCAP;
    for (u32 i = part * 512 + t; i < n; i += 1024) {
        const uint2 ent = q[i];
        const int row = (int)(ent.x >> 13);
        const u32 r = (u32)(row - rlo);
        if (r >= 64u) continue;                // other half's row
        const int col = (int)(ent.x & 8191u);
        const float s = __uint_as_float(ent.y);
        const float bound = cdec(bestC[row]);  // final global coarse min (finite)
        if (s > bound + CMARGIN) continue;

        // ---- bit-exact numpy fp32 replica (validated) -- z from LDS ----
        const float* er = emb + (size_t)col * DD;

        float A0 = 0.f, A1 = 0.f, A2 = 0.f, A3 = 0.f;
        float zh0 = 0.f, eh0 = 0.f, z2 = 0.f, e2 = 0.f;
#pragma unroll
        for (int h = 0; h < 2; ++h) {
            const int base = h * 128;
            float zv[8], ev[8], rz[8], re[8];
#pragma unroll
            for (int q2 = 0; q2 < 8; ++q2) { zv[q2] = zl[base + q2][r]; ev[q2] = er[base + q2]; }
#pragma unroll
            for (int q2 = 0; q2 < 8; ++q2) { rz[q2] = __fmul_rn(zv[q2], zv[q2]); re[q2] = __fmul_rn(ev[q2], ev[q2]); }
            A0 = __fadd_rn(A0, __fmul_rn(zv[0], ev[0])); A1 = __fadd_rn(A1, __fmul_rn(zv[1], ev[1]));
            A2 = __fadd_rn(A2, __fmul_rn(zv[2], ev[2])); A3 = __fadd_rn(A3, __fmul_rn(zv[3], ev[3]));
            A0 = __fadd_rn(A0, __fmul_rn(zv[4], ev[4])); A1 = __fadd_rn(A1, __fmul_rn(zv[5], ev[5]));
            A2 = __fadd_rn(A2, __fmul_rn(zv[6], ev[6])); A3 = __fadd_rn(A3, __fmul_rn(zv[7], ev[7]));
            for (int i2 = 8; i2 < 128; i2 += 8) {
#pragma unroll
                for (int q2 = 0; q2 < 8; ++q2) { zv[q2] = zl[base + i2 + q2][r]; ev[q2] = er[base + i2 + q2]; }
#pragma unroll
                for (int q2 = 0; q2 < 8; ++q2) {
                    rz[q2] = __fadd_rn(rz[q2], __fmul_rn(zv[q2], zv[q2]));
                    re[q2] = __fadd_rn(re[q2], __fmul_rn(ev[q2], ev[q2]));
                }
                A0 = __fadd_rn(A0, __fmul_rn(zv[0], ev[0])); A1 = __fadd_rn(A1, __fmul_rn(zv[1], ev[1]));
                A2 = __fadd_rn(A2, __fmul_rn(zv[2], ev[2])); A3 = __fadd_rn(A3, __fmul_rn(zv[3], ev[3]));
                A0 = __fadd_rn(A0, __fmul_rn(zv[4], ev[4])); A1 = __fadd_rn(A1, __fmul_rn(zv[5], ev[5]));
                A2 = __fadd_rn(A2, __fmul_rn(zv[6], ev[6])); A3 = __fadd_rn(A3, __fmul_rn(zv[7], ev[7]));
            }
            float cz = __fadd_rn(__fadd_rn(__fadd_rn(rz[0], rz[1]), __fadd_rn(rz[2], rz[3])),
                                 __fadd_rn(__fadd_rn(rz[4], rz[5]), __fadd_rn(rz[6], rz[7])));
            float ce = __fadd_rn(__fadd_rn(__fadd_rn(re[0], re[1]), __fadd_rn(re[2], re[3])),
                                 __fadd_rn(__fadd_rn(re[4], re[5]), __fadd_rn(re[6], re[7])));
            if (h == 0) { zh0 = cz; eh0 = ce; }
            else        { z2 = __fadd_rn(zh0, cz); e2 = __fadd_rn(eh0, ce); }
        }
        const float dot = __fadd_rn(__fadd_rn(A0, A1), __fadd_rn(A2, A3));
        const float S   = __fadd_rn(z2, e2);
        const float d   = __fsub_rn(S, __fmul_rn(2.0f, dot));

        const u32 db = __float_as_uint(d);
        const u32 kd = (db & 0x80000000u) ? ~db : (db | 0x80000000u);
        const unsigned long long pk = (((unsigned long long)kd) << 24) | (unsigned long long)col;
        atomicMin(rowBest + row, pk);   // fp32-equal d -> smaller col = numpy first-index
    }
}

// Fused gather + ids.  Block = (64-hw tile, b, c-quarter).  h2==0 blocks also
// emit the ids output from the already-loaded idr[].  Fused fp64 loss partial.
__global__ __launch_bounds__(256)
void k_gather(const float* __restrict__ z, const float* __restrict__ emb,
              const unsigned long long* __restrict__ rowBest,
              float* __restrict__ outZq, double* __restrict__ lossSum,
              float* __restrict__ outIds) {   // outIds = out + ZQ_N + 3
    __shared__ float lt[64][65];
    __shared__ u32 idr[64];
    __shared__ double red[4];
    const int t = threadIdx.x;
    const int hw0 = blockIdx.x * 64, b = blockIdx.y;
    const int h2 = blockIdx.z;                // channel quarter 0..3
    const int w = t >> 6, l = t & 63;

    if (t < 64) {
        u32 id = (u32)(rowBest[b * HWD + hw0 + t] & 0xFFFFFFULL) & (KK - 1);
        idr[t] = id;
        if (h2 == 0) outIds[b * HWD + hw0 + t] = (float)id;   // ids output
    }
    __syncthreads();

    const int rr = t >> 6, cc = t & 63;       // 4 rows staged per sweep
    for (int s = 0; s < 16; ++s) {
        const int r = s * 4 + rr;
        lt[r][cc] = emb[(size_t)idr[r] * DD + h2 * 64 + cc];
    }
    __syncthreads();

    double lsum = 0.0;
#pragma unroll
    for (int i = 0; i < 16; ++i) {
        const int cl = i * 4 + w;
        const int c  = h2 * 64 + cl;
        const size_t f = ((size_t)(b * CC + c)) * HWD + hw0 + l;
        const float zq = lt[l][cl];
        const float zv = z[f];
        outZq[f] = zq;
        const double dif = (double)zq - (double)zv;
        lsum += dif * dif;
    }
#pragma unroll
    for (int o = 32; o; o >>= 1) lsum += __shfl_down(lsum, o);
    if (l == 0) red[w] = lsum;
    __syncthreads();
    if (t == 0) atomicAdd(lossSum, red[0] + red[1] + red[2] + red[3]);
}

__global__ void k_loss(const double* __restrict__ lossSum, float* __restrict__ outLoss) {
    double m = *lossSum / (double)ZQ_N;
    outLoss[0] = (float)(1.25 * m);   // loss = commitment + codebook
    outLoss[1] = (float)(0.25 * m);   // commitment (cost 0.25)
    outLoss[2] = (float)m;            // codebook
}

extern "C" void kernel_launch(void* const* d_in, const int* in_sizes, int n_in,
                              void* d_out, int out_size, void* d_ws, size_t ws_size,
                              hipStream_t stream) {
    const float* z   = (const float*)d_in[0];
    const float* emb = (const float*)d_in[1];
    float* out = (float*)d_out;
    char* ws = (char*)d_ws;

    if (ws_size < (size_t)WS_NEEDED) return;

    unsigned long long* rowBest = (unsigned long long*)(ws + WS_ROWBEST);
    double*             lossSum = (double*)(ws + WS_LOSS);
    u16*   zb     = (u16*)(out + ZB_OFF);
    u16*   eb     = (u16*)(out + EB_OFF);
    uint2* queue  = (uint2*)(out + Q_OFF);
    u32*   segCnt = (u32*)(out + SEGCNT_OFF);
    u32*   bestC  = (u32*)(out + BC_OFF);

    hipLaunchKernelGGL(k_prep,    dim3(3136),        dim3(256), 0, stream,
                       z, emb, zb, eb, rowBest, lossSum, bestC, segCnt);
    hipLaunchKernelGGL(k_gemm,    dim3(8192),        dim3(256), 0, stream, zb, eb, bestC, segCnt, queue);
    hipLaunchKernelGGL(k_rescore, dim3(512),         dim3(512), 0, stream, z, emb, queue, segCnt, bestC, rowBest);
    hipLaunchKernelGGL(k_gather,  dim3(16, 16, 4),   dim3(256), 0, stream,
                       z, emb, rowBest, out, lossSum, out + ZQ_N + 3);
    hipLaunchKernelGGL(k_loss,    dim3(1),           dim3(1),   0, stream, lossSum, out + ZQ_N);
}